// Round 5
// baseline (1258.832 us; speedup 1.0000x reference)
//
#include <hip/hip_runtime.h>
#include <hip/hip_bf16.h>
#include <math.h>

#define N_NODES 50000
#define N_PAD   50048   // 391 * 128
#define N_EDGES 800000
#define ES      850000  // edges + self loops
#define HEADS 4

typedef __attribute__((ext_vector_type(8))) short short8_t;
typedef __attribute__((ext_vector_type(4))) float f32x4;

// Exact 3-way bf16 split: v == p0 + p1 + p2 (f32 mantissa = 3 x 8 bits).
__device__ inline void split3(float v, ushort& p0, ushort& p1, ushort& p2) {
    unsigned u = __float_as_uint(v);
    p0 = (ushort)(u >> 16);
    float r = v - __uint_as_float(u & 0xffff0000u);
    unsigned u1 = __float_as_uint(r);
    p1 = (ushort)(u1 >> 16);
    float r2 = r - __uint_as_float(u1 & 0xffff0000u);
    p2 = (ushort)(__float_as_uint(r2) >> 16);
}

// Fragment-major plane layout: 16-row x 8-k tiles, ktile-major within rowtile:
// off(row,k; nkt) = ((row/16)*nkt + k/8)*128 + (row%16)*8 + (k%8)
__device__ inline size_t tiled_off(int row, int k, int nkt) {
    return ((size_t)(row >> 4) * nkt + (k >> 3)) * 128 + ((row & 15) << 3) + (k & 7);
}

// ---------------------------------------------------------------------------
// CSR construction
// ---------------------------------------------------------------------------

__global__ void init_deg_kernel(int* __restrict__ deg) {
    int i = blockIdx.x * blockDim.x + threadIdx.x;
    if (i < N_NODES) deg[i] = 1;  // self-loop
}

__global__ void hist_kernel(const int* __restrict__ dst, int* __restrict__ deg) {
    int i = blockIdx.x * blockDim.x + threadIdx.x;
    if (i < N_EDGES) atomicAdd(&deg[dst[i]], 1);
}

__global__ __launch_bounds__(1024) void scan_kernel(const int* __restrict__ deg,
                                                    int* __restrict__ rowptr,
                                                    int* __restrict__ cursor) {
    __shared__ int sums[1024];
    const int t = threadIdx.x;
    const int CHUNK = (N_NODES + 1023) / 1024;
    int begin = t * CHUNK;
    int end = begin + CHUNK; if (end > N_NODES) end = N_NODES;
    if (begin > N_NODES) begin = N_NODES;

    int s = 0;
    for (int i = begin; i < end; ++i) s += deg[i];
    sums[t] = s;
    __syncthreads();
    for (int off = 1; off < 1024; off <<= 1) {
        int v = (t >= off) ? sums[t - off] : 0;
        __syncthreads();
        sums[t] += v;
        __syncthreads();
    }
    int run = (t == 0) ? 0 : sums[t - 1];
    for (int i = begin; i < end; ++i) {
        int d = deg[i];          // read BEFORE aliased write
        rowptr[i] = run;
        cursor[i] = run;
        run += d;
    }
    if (t == 1023) rowptr[N_NODES] = run;
}

__global__ void scatter_kernel(const int* __restrict__ src, const int* __restrict__ dst,
                               int* __restrict__ cursor, int* __restrict__ col,
                               int* __restrict__ dste) {
    int i = blockIdx.x * blockDim.x + threadIdx.x;
    if (i < N_EDGES) {
        int d = dst[i];
        int pos = atomicAdd(&cursor[d], 1);
        col[pos] = src[i];
        dste[pos] = d;
    } else if (i < N_EDGES + N_NODES) {
        int n = i - N_EDGES;
        int pos = atomicAdd(&cursor[n], 1);
        col[pos] = n;
        dste[pos] = n;
    }
}

// ---------------------------------------------------------------------------
// Splitters (write fragment-major tiled planes)
// ---------------------------------------------------------------------------

__global__ void x_split_kernel(const float* __restrict__ x, ushort* __restrict__ pl,
                               size_t pstride) {
    int i = blockIdx.x * blockDim.x + threadIdx.x;
    if (i >= N_NODES * 64) return;
    int n = i >> 6, k = i & 63;
    ushort a, b, c;
    split3(x[i], a, b, c);
    size_t off = tiled_off(n, k, 8);   // layer-0 K=64 -> nkt=8
    pl[off] = a;
    pl[pstride + off] = b;
    pl[2 * pstride + off] = c;
}

__global__ void w_split_kernel(const float* __restrict__ W, ushort* __restrict__ wt,
                               int K, int NC) {
    int t = blockIdx.x * blockDim.x + threadIdx.x;  // 65536 = 256 cols x 256 k
    int c = t >> 8, k = t & 255;
    float v = (k < K && c < NC) ? W[k * NC + c] : 0.f;
    ushort a, b, cc;
    split3(v, a, b, cc);
    size_t off = tiled_off(c, k, 32);  // B padded to 256 k -> nkt=32
    wt[off] = a;
    wt[65536 + off] = b;
    wt[131072 + off] = cc;
}

// ---------------------------------------------------------------------------
// bf16x3 MFMA GEMM, zero-LDS: fragments loaded directly from tiled planes.
// Block 128x128, 4 waves (2x2 of 64x64), mfma_f32_16x16x32_bf16.
// ---------------------------------------------------------------------------

template <int KT, int FUSE_ATTN>
__global__ __launch_bounds__(256, 2) void gemm_mfma_kernel(
        const ushort* __restrict__ Apl, size_t apstride, int nkt,
        const ushort* __restrict__ Wt,   // tiled [3][16coltiles][32ktiles][16][8]
        float* __restrict__ C, int NC,
        const float* __restrict__ as_flat, const float* __restrict__ ad_flat,
        float* __restrict__ asn, float* __restrict__ adn) {
    const int tid = threadIdx.x;
    const int lane = tid & 63;
    const int wave = tid >> 6;
    const int wr = (wave >> 1) * 64;
    const int wc = (wave & 1) * 64;
    const int m0 = blockIdx.x * 128;
    const int n0 = blockIdx.y * 128;
    const int rta = (m0 + wr) >> 4;    // A rowtile base; frag i -> rta+i
    const int ctb = (n0 + wc) >> 4;    // B coltile base; frag j -> ctb+j

    const ushort* abase = Apl + (size_t)(rta * nkt) * 128 + lane * 8;
    const ushort* bbase = Wt + (size_t)(ctb * 32) * 128 + lane * 8;

    f32x4 acc[4][4];
#pragma unroll
    for (int i = 0; i < 4; ++i)
#pragma unroll
        for (int j = 0; j < 4; ++j) acc[i][j] = (f32x4){0.f, 0.f, 0.f, 0.f};

    short8_t afc[3][4], bf[3][4];
#pragma unroll
    for (int p = 0; p < 3; ++p)
#pragma unroll
        for (int i = 0; i < 4; ++i)
            afc[p][i] = *(const short8_t*)(abase + p * apstride + (size_t)(i * nkt) * 128);

#pragma unroll
    for (int k0 = 0; k0 < KT; k0 += 32) {
        const int kt0 = k0 >> 3;
        // B fragments (L2-resident weight planes)
#pragma unroll
        for (int p = 0; p < 3; ++p)
#pragma unroll
            for (int j = 0; j < 4; ++j)
                bf[p][j] = *(const short8_t*)(bbase + p * 65536 + (j * 32 + kt0) * 128);

        // A next-kstep register prefetch (stream from HBM hides under MFMA)
        short8_t afn[3][4];
        if (k0 + 32 < KT) {
#pragma unroll
            for (int p = 0; p < 3; ++p)
#pragma unroll
                for (int i = 0; i < 4; ++i)
                    afn[p][i] = *(const short8_t*)(abase + p * apstride +
                                                   (size_t)(i * nkt + kt0 + 4) * 128);
        }

#pragma unroll
        for (int i = 0; i < 4; ++i)
#pragma unroll
            for (int j = 0; j < 4; ++j) {
                f32x4 c = acc[i][j];
                c = __builtin_amdgcn_mfma_f32_16x16x32_bf16(afc[0][i], bf[0][j], c, 0, 0, 0);
                c = __builtin_amdgcn_mfma_f32_16x16x32_bf16(afc[0][i], bf[1][j], c, 0, 0, 0);
                c = __builtin_amdgcn_mfma_f32_16x16x32_bf16(afc[1][i], bf[0][j], c, 0, 0, 0);
                c = __builtin_amdgcn_mfma_f32_16x16x32_bf16(afc[0][i], bf[2][j], c, 0, 0, 0);
                c = __builtin_amdgcn_mfma_f32_16x16x32_bf16(afc[1][i], bf[1][j], c, 0, 0, 0);
                c = __builtin_amdgcn_mfma_f32_16x16x32_bf16(afc[2][i], bf[0][j], c, 0, 0, 0);
                acc[i][j] = c;
            }

        if (k0 + 32 < KT) {
#pragma unroll
            for (int p = 0; p < 3; ++p)
#pragma unroll
                for (int i = 0; i < 4; ++i) afc[p][i] = afn[p][i];
        }
    }

    // epilogue: C/D mapping col = lane&15, row = (lane>>4)*4 + reg
    const int rbase = m0 + wr + (lane >> 4) * 4;
    const int cbase = n0 + wc + (lane & 15);
#pragma unroll
    for (int i = 0; i < 4; ++i)
#pragma unroll
        for (int j = 0; j < 4; ++j) {
            int gcol = cbase + j * 16;
            if (gcol >= NC) continue;
#pragma unroll
            for (int r4 = 0; r4 < 4; ++r4) {
                int grow = rbase + i * 16 + r4;
                if (grow < N_NODES) C[(size_t)grow * NC + gcol] = acc[i][j][r4];
            }
        }

    if (FUSE_ATTN) {
        // this wave's 64 cols == head (n0+wc)>>6 (CH=64)
        const int hd_out = (n0 + wc) >> 6;
        float as_v[4], ad_v[4];
#pragma unroll
        for (int j = 0; j < 4; ++j) {
            int gc = cbase + j * 16;
            as_v[j] = as_flat[gc];
            ad_v[j] = ad_flat[gc];
        }
#pragma unroll
        for (int i = 0; i < 4; ++i)
#pragma unroll
            for (int r4 = 0; r4 < 4; ++r4) {
                float ps = 0.f, pd = 0.f;
#pragma unroll
                for (int j = 0; j < 4; ++j) {
                    float v = acc[i][j][r4];
                    ps += v * as_v[j];
                    pd += v * ad_v[j];
                }
#pragma unroll
                for (int o = 1; o < 16; o <<= 1) {
                    ps += __shfl_xor(ps, o);
                    pd += __shfl_xor(pd, o);
                }
                if ((lane & 15) == 0) {
                    int grow = rbase + i * 16 + r4;
                    if (grow < N_NODES) {
                        asn[grow * 4 + hd_out] = ps;
                        adn[grow * 4 + hd_out] = pd;
                    }
                }
            }
    }
}

// ---------------------------------------------------------------------------
// Standalone attention coefficients (layer 4 only, CH=10)
// ---------------------------------------------------------------------------

__global__ void attn_coef_kernel(const float* __restrict__ h,
                                 const float* __restrict__ a_s,
                                 const float* __restrict__ a_d,
                                 float* __restrict__ asn, float* __restrict__ adn,
                                 int CH) {
    int t = blockIdx.x * blockDim.x + threadIdx.x;
    if (t >= N_NODES * HEADS) return;
    int n = t >> 2;
    int hd = t & 3;
    const float* hp = h + (size_t)n * HEADS * CH + hd * CH;
    const float* sp = a_s + hd * CH;
    const float* dp = a_d + hd * CH;
    float s1 = 0.f, s2 = 0.f;
    for (int c = 0; c < CH; c += 2) {
        float2 hv = *reinterpret_cast<const float2*>(&hp[c]);
        float2 av = *reinterpret_cast<const float2*>(&sp[c]);
        float2 dv = *reinterpret_cast<const float2*>(&dp[c]);
        s1 += hv.x * av.x + hv.y * av.y;
        s2 += hv.x * dv.x + hv.y * dv.y;
    }
    asn[t] = s1;
    adn[t] = s2;
}

// ---------------------------------------------------------------------------
// Edge coefficients: e_h[hd][e] = leaky_relu(asn[col[e],hd] + adn[dste[e],hd])
// One 16B asn gather per edge covers all 4 heads; adn reads are dst-sorted.
// ---------------------------------------------------------------------------

__global__ void edge_coef_kernel(const int* __restrict__ col, const int* __restrict__ dste,
                                 const float* __restrict__ asn, const float* __restrict__ adn,
                                 float* __restrict__ e_h) {
    int e = blockIdx.x * blockDim.x + threadIdx.x;
    if (e >= ES) return;
    int s = col[e], d = dste[e];
    float4 a = *reinterpret_cast<const float4*>(&asn[s * 4]);
    float4 b = *reinterpret_cast<const float4*>(&adn[d * 4]);
    float4 v = make_float4(a.x + b.x, a.y + b.y, a.z + b.z, a.w + b.w);
    v.x = (v.x > 0.f) ? v.x : 0.2f * v.x;
    v.y = (v.y > 0.f) ? v.y : 0.2f * v.y;
    v.z = (v.z > 0.f) ? v.z : 0.2f * v.z;
    v.w = (v.w > 0.f) ? v.w : 0.2f * v.w;
    e_h[e] = v.x;
    e_h[ES + e] = v.y;
    e_h[2 * ES + e] = v.z;
    e_h[3 * ES + e] = v.w;
}

// ---------------------------------------------------------------------------
// Batched online-softmax aggregation, coalesced e_h reads.
// EMIT=1 -> write 3 bf16 planes in fragment-major tiled layout (nkt=32).
// ---------------------------------------------------------------------------

template <int CH, int EMIT>
__global__ __launch_bounds__(256) void aggregate_kernel(
        const float* __restrict__ h, const float* __restrict__ e_h,
        const int* __restrict__ rowptr, const int* __restrict__ col,
        const float* __restrict__ bias,
        ushort* __restrict__ pl, size_t pstride, float* __restrict__ out) {
    constexpr int HC = HEADS * CH;
    __shared__ float2 pair_lds[HEADS][32];

    const int n = blockIdx.x;
    const int hd = threadIdx.x >> 6;
    const int lane = threadIdx.x & 63;
    const int el = lane & 31;

    const int start = rowptr[n];
    const int end = rowptr[n + 1];

    float m = -INFINITY, s = 0.f, acc0 = 0.f, acc1 = 0.f;

    for (int e0 = start; e0 < end; e0 += 32) {
        int e = e0 + el;
        bool valid = (lane < 32) && (e < end);
        int srcl = n;
        float ev = -INFINITY;
        if (valid) {
            srcl = col[e];
            ev = e_h[hd * ES + e];
        }
        float bm = ev;
#pragma unroll
        for (int o = 1; o < 64; o <<= 1) bm = fmaxf(bm, __shfl_xor(bm, o));
        float mn = fmaxf(m, bm);
        float scale = __expf(m - mn);
        float p = __expf(ev - mn);
        float ps = p;
#pragma unroll
        for (int o = 1; o < 64; o <<= 1) ps += __shfl_xor(ps, o);
        s = s * scale + ps;
        acc0 *= scale;
        acc1 *= scale;
        m = mn;

        if (lane < 32) pair_lds[hd][lane] = make_float2(__int_as_float(srcl), p);

        int cnt = end - e0; if (cnt > 32) cnt = 32;
        int cnt8 = (cnt + 7) & ~7;
        for (int i = 0; i < cnt8; i += 8) {
#pragma unroll
            for (int j = 0; j < 8; j += 2) {
                float2 pr0 = pair_lds[hd][i + j];
                float2 pr1 = pair_lds[hd][i + j + 1];
                int s0 = __float_as_int(pr0.x);
                int s1 = __float_as_int(pr1.x);
                float hv0 = (lane < CH) ? h[s0 * HC + hd * CH + lane] : 0.f;
                float hv1 = (lane < CH) ? h[s1 * HC + hd * CH + lane] : 0.f;
                acc0 += pr0.y * hv0;
                acc1 += pr1.y * hv1;
            }
        }
    }

    if (lane < CH) {
        float v = (acc0 + acc1) / (s + 1e-16f) + bias[hd * CH + lane];
        v = fmaxf(v, 0.f);
        if (EMIT) {
            ushort a, b, c;
            split3(v, a, b, c);
            int k = hd * CH + lane;              // feature column (CH=64 here)
            size_t off = tiled_off(n, k, 32);    // next layer K=256 -> nkt=32
            pl[off] = a;
            pl[pstride + off] = b;
            pl[2 * pstride + off] = c;
        } else {
            out[n * HC + hd * CH + lane] = v;
        }
    }
}

// ---------------------------------------------------------------------------

extern "C" void kernel_launch(void* const* d_in, const int* in_sizes, int n_in,
                              void* d_out, int out_size, void* d_ws, size_t ws_size,
                              hipStream_t stream) {
    const float* x_in = (const float*)d_in[0];
    const int* ei = (const int*)d_in[1];
    const int* src = ei;
    const int* dst = ei + N_EDGES;

    const float *W[5], *AS[5], *AD[5], *BI[5];
    for (int l = 0; l < 5; ++l) {
        W[l]  = (const float*)d_in[2 + l * 4 + 0];
        AS[l] = (const float*)d_in[2 + l * 4 + 1];
        AD[l] = (const float*)d_in[2 + l * 4 + 2];
        BI[l] = (const float*)d_in[2 + l * 4 + 3];
    }

    // workspace carve-up
    const size_t PSTRIDE = (size_t)N_PAD * 256;           // elements per plane
    ushort* planes = (ushort*)d_ws;                       // 3 tiled bf16 planes
    float* Hb   = (float*)(planes + 3 * PSTRIDE);         // N x 256 f32
    float* asn  = Hb + (size_t)N_NODES * 256;
    float* adn  = asn + (size_t)N_NODES * HEADS;
    float* e_h  = adn + (size_t)N_NODES * HEADS;          // [4][ES]
    int* rowptr = (int*)(e_h + (size_t)4 * ES);           // N+1
    int* cursor = rowptr + (N_NODES + 1);
    int* col    = cursor + N_NODES;                       // ES
    int* dste   = col + ES;                               // ES
    ushort* wt  = (ushort*)(((uintptr_t)(dste + ES) + 15) & ~(uintptr_t)15);

    // --- CSR build ---
    init_deg_kernel<<<(N_NODES + 255) / 256, 256, 0, stream>>>(cursor);
    hist_kernel<<<(N_EDGES + 255) / 256, 256, 0, stream>>>(dst, cursor);
    scan_kernel<<<1, 1024, 0, stream>>>(cursor, rowptr, cursor);
    scatter_kernel<<<(N_EDGES + N_NODES + 255) / 256, 256, 0, stream>>>(src, dst, cursor, col, dste);

    // --- weight & input splits (tiled layouts) ---
    for (int l = 0; l < 5; ++l) {
        int Kl = (l == 0) ? 64 : 256;
        int NCl = (l == 4) ? 40 : 256;
        w_split_kernel<<<256, 256, 0, stream>>>(W[l], wt + (size_t)l * 3 * 65536, Kl, NCl);
    }
    x_split_kernel<<<(N_NODES * 64 + 255) / 256, 256, 0, stream>>>(x_in, planes, PSTRIDE);

    // --- 5 GAT layers ---
    for (int l = 0; l < 5; ++l) {
        const int NC = (l == 4) ? 40 : 256;
        const int nkt = (l == 0) ? 8 : 32;
        dim3 ggrid(N_PAD / 128, (NC + 127) / 128);
        const ushort* wl = wt + (size_t)l * 3 * 65536;
        if (l == 0) {
            gemm_mfma_kernel<64, 1><<<ggrid, 256, 0, stream>>>(
                planes, PSTRIDE, nkt, wl, Hb, NC, AS[l], AD[l], asn, adn);
        } else if (l < 4) {
            gemm_mfma_kernel<256, 1><<<ggrid, 256, 0, stream>>>(
                planes, PSTRIDE, nkt, wl, Hb, NC, AS[l], AD[l], asn, adn);
        } else {
            gemm_mfma_kernel<256, 0><<<ggrid, 256, 0, stream>>>(
                planes, PSTRIDE, nkt, wl, Hb, NC, AS[l], AD[l], asn, adn);
            attn_coef_kernel<<<(N_NODES * HEADS + 255) / 256, 256, 0, stream>>>(
                Hb, AS[l], AD[l], asn, adn, 10);
        }
        edge_coef_kernel<<<(ES + 255) / 256, 256, 0, stream>>>(col, dste, asn, adn, e_h);
        if (l < 4) {
            aggregate_kernel<64, 1><<<N_NODES, 256, 0, stream>>>(
                Hb, e_h, rowptr, col, BI[l], planes, PSTRIDE, nullptr);
        } else {
            aggregate_kernel<10, 0><<<N_NODES, 256, 0, stream>>>(
                Hb, e_h, rowptr, col, BI[l], nullptr, 0, (float*)d_out);
        }
    }
    (void)in_sizes; (void)n_in; (void)out_size; (void)ws_size;
}

// Round 6
// 1034.024 us; speedup vs baseline: 1.2174x; 1.2174x over previous
//
#include <hip/hip_runtime.h>
#include <hip/hip_bf16.h>
#include <math.h>

#define N_NODES 50000
#define N_PAD   50048   // 391 * 128
#define N_EDGES 800000
#define HEADS 4

typedef __attribute__((ext_vector_type(8))) _Float16 half8_t;
typedef __attribute__((ext_vector_type(4))) float f32x4;

// 2-way f16 split: v ~= (float)p0 + (float)p1, exact to ~2^-23 relative.
__device__ inline void split2(float v, _Float16& p0, _Float16& p1) {
    p0 = (_Float16)v;
    p1 = (_Float16)(v - (float)p0);
}

// ---------------------------------------------------------------------------
// CSR construction
// ---------------------------------------------------------------------------

__global__ void init_deg_kernel(int* __restrict__ deg) {
    int i = blockIdx.x * blockDim.x + threadIdx.x;
    if (i < N_NODES) deg[i] = 1;  // self-loop
}

__global__ void hist_kernel(const int* __restrict__ dst, int* __restrict__ deg) {
    int i = blockIdx.x * blockDim.x + threadIdx.x;
    if (i < N_EDGES) atomicAdd(&deg[dst[i]], 1);
}

__global__ __launch_bounds__(1024) void scan_kernel(const int* __restrict__ deg,
                                                    int* __restrict__ rowptr,
                                                    int* __restrict__ cursor) {
    __shared__ int sums[1024];
    const int t = threadIdx.x;
    const int CHUNK = (N_NODES + 1023) / 1024;
    int begin = t * CHUNK;
    int end = begin + CHUNK; if (end > N_NODES) end = N_NODES;
    if (begin > N_NODES) begin = N_NODES;

    int s = 0;
    for (int i = begin; i < end; ++i) s += deg[i];
    sums[t] = s;
    __syncthreads();
    for (int off = 1; off < 1024; off <<= 1) {
        int v = (t >= off) ? sums[t - off] : 0;
        __syncthreads();
        sums[t] += v;
        __syncthreads();
    }
    int run = (t == 0) ? 0 : sums[t - 1];
    for (int i = begin; i < end; ++i) {
        int d = deg[i];          // read BEFORE aliased write
        rowptr[i] = run;
        cursor[i] = run;
        run += d;
    }
    if (t == 1023) rowptr[N_NODES] = run;
}

__global__ void scatter_kernel(const int* __restrict__ src, const int* __restrict__ dst,
                               int* __restrict__ cursor, int* __restrict__ col) {
    int i = blockIdx.x * blockDim.x + threadIdx.x;
    if (i < N_EDGES) {
        int d = dst[i];
        int pos = atomicAdd(&cursor[d], 1);
        col[pos] = src[i];
    } else if (i < N_EDGES + N_NODES) {
        int n = i - N_EDGES;
        int pos = atomicAdd(&cursor[n], 1);
        col[pos] = n;
    }
}

// ---------------------------------------------------------------------------
// Splitters (row-major planes)
// ---------------------------------------------------------------------------

__global__ void x_split_kernel(const float* __restrict__ x, _Float16* __restrict__ pl,
                               size_t pstride) {
    int i = blockIdx.x * blockDim.x + threadIdx.x;
    if (i >= N_NODES * 64) return;
    _Float16 a, b;
    split2(x[i], a, b);
    pl[i] = a;
    pl[pstride + i] = b;
}

__global__ void w_split_kernel(const float* __restrict__ W, _Float16* __restrict__ wt,
                               int K, int NC) {
    int t = blockIdx.x * blockDim.x + threadIdx.x;  // 65536 = 256 cols x 256 k
    int c = t >> 8, k = t & 255;
    float v = (k < K && c < NC) ? W[k * NC + c] : 0.f;
    _Float16 a, b;
    split2(v, a, b);
    wt[t] = a;           // Wt[col][k] row-major in col
    wt[65536 + t] = b;
}

// ---------------------------------------------------------------------------
// f16x2 MFMA GEMM, reg-prefetch pipelined; optional fused attn-coef epilogue
// (CH==64 layers: each 64-col wave quarter == exactly one head).
// Block 128x128, 4 waves (2x2 of 64x64), BK=32, mfma_f32_16x16x32_f16,
// 3 MFMAs per (i,j): a0b0 + a0b1 + a1b0  (a1b1 ~ 2^-22, dropped).
// ---------------------------------------------------------------------------

template <int FUSE_ATTN>
__global__ __launch_bounds__(256) void gemm_mfma_kernel(
        const _Float16* __restrict__ Apl, size_t apstride, int lda,
        const _Float16* __restrict__ Wt,   // [2][256 cols][256 k], zero-padded
        float* __restrict__ C, int K, int NC,
        const float* __restrict__ as_flat, const float* __restrict__ ad_flat,
        float* __restrict__ asn, float* __restrict__ adn) {
    __shared__ _Float16 As[2][128][40];   // stride 80B: 16B-aligned, 2-way banks
    __shared__ _Float16 Bs[2][128][40];

    const int tid = threadIdx.x;
    const int lane = tid & 63;
    const int wave = tid >> 6;
    const int wr = (wave >> 1) * 64;
    const int wc = (wave & 1) * 64;
    const int m0 = blockIdx.x * 128;
    const int n0 = blockIdx.y * 128;

    f32x4 acc[4][4];
#pragma unroll
    for (int i = 0; i < 4; ++i)
#pragma unroll
        for (int j = 0; j < 4; ++j) acc[i][j] = (f32x4){0.f, 0.f, 0.f, 0.f};

    const int row0 = tid >> 2, q = tid & 3;
    const int row1 = row0 + 64;

    const _Float16* aptr0 = Apl + (size_t)(m0 + row0) * lda + q * 8;
    const _Float16* aptr1 = Apl + (size_t)(m0 + row1) * lda + q * 8;
    const _Float16* bptr0 = Wt + (size_t)(n0 + row0) * 256 + q * 8;
    const _Float16* bptr1 = Wt + (size_t)(n0 + row1) * 256 + q * 8;

    half8_t pa[2][2], pb[2][2];
#pragma unroll
    for (int p = 0; p < 2; ++p) {
        pa[p][0] = *(const half8_t*)(aptr0 + p * apstride);
        pa[p][1] = *(const half8_t*)(aptr1 + p * apstride);
        pb[p][0] = *(const half8_t*)(bptr0 + p * 65536);
        pb[p][1] = *(const half8_t*)(bptr1 + p * 65536);
    }

    for (int k0 = 0; k0 < K; k0 += 32) {
        if (k0) __syncthreads();   // prev-iter LDS readers done
#pragma unroll
        for (int p = 0; p < 2; ++p) {
            *(half8_t*)(&As[p][row0][q * 8]) = pa[p][0];
            *(half8_t*)(&As[p][row1][q * 8]) = pa[p][1];
            *(half8_t*)(&Bs[p][row0][q * 8]) = pb[p][0];
            *(half8_t*)(&Bs[p][row1][q * 8]) = pb[p][1];
        }
        __syncthreads();

        // issue next-tile global loads early: latency hides under ds_read+MFMA
        if (k0 + 32 < K) {
            int kn = k0 + 32;
#pragma unroll
            for (int p = 0; p < 2; ++p) {
                pa[p][0] = *(const half8_t*)(aptr0 + p * apstride + kn);
                pa[p][1] = *(const half8_t*)(aptr1 + p * apstride + kn);
                pb[p][0] = *(const half8_t*)(bptr0 + p * 65536 + kn);
                pb[p][1] = *(const half8_t*)(bptr1 + p * 65536 + kn);
            }
        }

        half8_t bf[2][4];
#pragma unroll
        for (int p = 0; p < 2; ++p)
#pragma unroll
            for (int j = 0; j < 4; ++j)
                bf[p][j] = *(const half8_t*)(&Bs[p][wc + j * 16 + (lane & 15)][(lane >> 4) * 8]);

#pragma unroll
        for (int i = 0; i < 4; ++i) {
            half8_t af0 = *(const half8_t*)(&As[0][wr + i * 16 + (lane & 15)][(lane >> 4) * 8]);
            half8_t af1 = *(const half8_t*)(&As[1][wr + i * 16 + (lane & 15)][(lane >> 4) * 8]);
#pragma unroll
            for (int j = 0; j < 4; ++j) {
                f32x4 c = acc[i][j];
                c = __builtin_amdgcn_mfma_f32_16x16x32_f16(af0, bf[1][j], c, 0, 0, 0);
                c = __builtin_amdgcn_mfma_f32_16x16x32_f16(af1, bf[0][j], c, 0, 0, 0);
                c = __builtin_amdgcn_mfma_f32_16x16x32_f16(af0, bf[0][j], c, 0, 0, 0);
                acc[i][j] = c;
            }
        }
    }

    // epilogue: C/D mapping col = lane&15, row = (lane>>4)*4 + reg
    const int rbase = m0 + wr + (lane >> 4) * 4;
    const int cbase = n0 + wc + (lane & 15);
#pragma unroll
    for (int i = 0; i < 4; ++i)
#pragma unroll
        for (int j = 0; j < 4; ++j) {
            int gcol = cbase + j * 16;
            if (gcol >= NC) continue;
#pragma unroll
            for (int r4 = 0; r4 < 4; ++r4) {
                int grow = rbase + i * 16 + r4;
                if (grow < N_NODES) C[(size_t)grow * NC + gcol] = acc[i][j][r4];
            }
        }

    if (FUSE_ATTN) {
        // this wave's 64 cols == head (n0+wc)>>6 (CH=64)
        const int hd_out = (n0 + wc) >> 6;
        float as_v[4], ad_v[4];
#pragma unroll
        for (int j = 0; j < 4; ++j) {
            int gc = cbase + j * 16;
            as_v[j] = as_flat[gc];
            ad_v[j] = ad_flat[gc];
        }
#pragma unroll
        for (int i = 0; i < 4; ++i)
#pragma unroll
            for (int r4 = 0; r4 < 4; ++r4) {
                float ps = 0.f, pd = 0.f;
#pragma unroll
                for (int j = 0; j < 4; ++j) {
                    float v = acc[i][j][r4];
                    ps += v * as_v[j];
                    pd += v * ad_v[j];
                }
#pragma unroll
                for (int o = 1; o < 16; o <<= 1) {
                    ps += __shfl_xor(ps, o);
                    pd += __shfl_xor(pd, o);
                }
                if ((lane & 15) == 0) {
                    int grow = rbase + i * 16 + r4;
                    if (grow < N_NODES) {
                        asn[grow * 4 + hd_out] = ps;
                        adn[grow * 4 + hd_out] = pd;
                    }
                }
            }
    }
}

// ---------------------------------------------------------------------------
// Standalone attention coefficients (layer 4 only, CH=10)
// ---------------------------------------------------------------------------

__global__ void attn_coef_kernel(const float* __restrict__ h,
                                 const float* __restrict__ a_s,
                                 const float* __restrict__ a_d,
                                 float* __restrict__ asn, float* __restrict__ adn,
                                 int CH) {
    int t = blockIdx.x * blockDim.x + threadIdx.x;
    if (t >= N_NODES * HEADS) return;
    int n = t >> 2;
    int hd = t & 3;
    const float* hp = h + (size_t)n * HEADS * CH + hd * CH;
    const float* sp = a_s + hd * CH;
    const float* dp = a_d + hd * CH;
    float s1 = 0.f, s2 = 0.f;
    for (int c = 0; c < CH; c += 2) {
        float2 hv = *reinterpret_cast<const float2*>(&hp[c]);
        float2 av = *reinterpret_cast<const float2*>(&sp[c]);
        float2 dv = *reinterpret_cast<const float2*>(&dp[c]);
        s1 += hv.x * av.x + hv.y * av.y;
        s2 += hv.x * dv.x + hv.y * dv.y;
    }
    asn[t] = s1;
    adn[t] = s2;
}

// ---------------------------------------------------------------------------
// Batched online-softmax aggregation; EMIT=1 -> write 2 f16 planes (row-major)
// ---------------------------------------------------------------------------

template <int CH, int EMIT>
__global__ __launch_bounds__(256) void aggregate_kernel(
        const float* __restrict__ h, const float* __restrict__ asn,
        const float* __restrict__ adn, const int* __restrict__ rowptr,
        const int* __restrict__ col, const float* __restrict__ bias,
        _Float16* __restrict__ pl, size_t pstride, float* __restrict__ out) {
    constexpr int HC = HEADS * CH;
    __shared__ float2 pair_lds[HEADS][32];

    const int n = blockIdx.x;
    const int hd = threadIdx.x >> 6;
    const int lane = threadIdx.x & 63;
    const int el = lane & 31;

    const int start = rowptr[n];
    const int end = rowptr[n + 1];
    const float adv = adn[(n << 2) | hd];

    float m = -INFINITY, s = 0.f, acc0 = 0.f, acc1 = 0.f;

    for (int e0 = start; e0 < end; e0 += 32) {
        int e = e0 + el;
        bool valid = (lane < 32) && (e < end);
        int srcl = n;
        float ev = -INFINITY;
        if (valid) {
            srcl = col[e];
            float t = asn[(srcl << 2) | hd] + adv;
            ev = (t > 0.f) ? t : 0.2f * t;
        }
        float bm = ev;
#pragma unroll
        for (int o = 1; o < 64; o <<= 1) bm = fmaxf(bm, __shfl_xor(bm, o));
        float mn = fmaxf(m, bm);
        float scale = __expf(m - mn);
        float p = __expf(ev - mn);
        float ps = p;
#pragma unroll
        for (int o = 1; o < 64; o <<= 1) ps += __shfl_xor(ps, o);
        s = s * scale + ps;
        acc0 *= scale;
        acc1 *= scale;
        m = mn;

        if (lane < 32) pair_lds[hd][lane] = make_float2(__int_as_float(srcl), p);

        int cnt = end - e0; if (cnt > 32) cnt = 32;
        int cnt8 = (cnt + 7) & ~7;
        for (int i = 0; i < cnt8; i += 8) {
#pragma unroll
            for (int j = 0; j < 8; j += 2) {
                float2 pr0 = pair_lds[hd][i + j];
                float2 pr1 = pair_lds[hd][i + j + 1];
                int s0 = __float_as_int(pr0.x);
                int s1 = __float_as_int(pr1.x);
                float hv0 = (lane < CH) ? h[s0 * HC + hd * CH + lane] : 0.f;
                float hv1 = (lane < CH) ? h[s1 * HC + hd * CH + lane] : 0.f;
                acc0 += pr0.y * hv0;
                acc1 += pr1.y * hv1;
            }
        }
    }

    if (lane < CH) {
        float v = (acc0 + acc1) / (s + 1e-16f) + bias[hd * CH + lane];
        v = fmaxf(v, 0.f);
        if (EMIT) {
            _Float16 a, b;
            split2(v, a, b);
            size_t off = (size_t)n * HC + hd * CH + lane;
            pl[off] = a;
            pl[pstride + off] = b;
        } else {
            out[n * HC + hd * CH + lane] = v;
        }
    }
}

// ---------------------------------------------------------------------------

extern "C" void kernel_launch(void* const* d_in, const int* in_sizes, int n_in,
                              void* d_out, int out_size, void* d_ws, size_t ws_size,
                              hipStream_t stream) {
    const float* x_in = (const float*)d_in[0];
    const int* ei = (const int*)d_in[1];
    const int* src = ei;
    const int* dst = ei + N_EDGES;

    const float *W[5], *AS[5], *AD[5], *BI[5];
    for (int l = 0; l < 5; ++l) {
        W[l]  = (const float*)d_in[2 + l * 4 + 0];
        AS[l] = (const float*)d_in[2 + l * 4 + 1];
        AD[l] = (const float*)d_in[2 + l * 4 + 2];
        BI[l] = (const float*)d_in[2 + l * 4 + 3];
    }

    // workspace carve-up
    const size_t PSTRIDE = (size_t)N_PAD * 256;           // elements per plane
    _Float16* planes = (_Float16*)d_ws;                   // 2 f16 planes
    float* Hb   = (float*)(planes + 2 * PSTRIDE);         // N x 256 f32
    float* asn  = Hb + (size_t)N_NODES * 256;
    float* adn  = asn + (size_t)N_NODES * HEADS;
    int* rowptr = (int*)(adn + (size_t)N_NODES * HEADS);  // N+1
    int* cursor = rowptr + (N_NODES + 1);
    int* col    = cursor + N_NODES;                       // E + N
    _Float16* wt = (_Float16*)(((uintptr_t)(col + N_EDGES + N_NODES) + 15) & ~(uintptr_t)15);

    // --- CSR build ---
    init_deg_kernel<<<(N_NODES + 255) / 256, 256, 0, stream>>>(cursor);
    hist_kernel<<<(N_EDGES + 255) / 256, 256, 0, stream>>>(dst, cursor);
    scan_kernel<<<1, 1024, 0, stream>>>(cursor, rowptr, cursor);
    scatter_kernel<<<(N_EDGES + N_NODES + 255) / 256, 256, 0, stream>>>(src, dst, cursor, col);

    // --- weight & input splits ---
    for (int l = 0; l < 5; ++l) {
        int Kl = (l == 0) ? 64 : 256;
        int NCl = (l == 4) ? 40 : 256;
        w_split_kernel<<<256, 256, 0, stream>>>(W[l], wt + (size_t)l * 2 * 65536, Kl, NCl);
    }
    x_split_kernel<<<(N_NODES * 64 + 255) / 256, 256, 0, stream>>>(x_in, planes, PSTRIDE);

    // --- 5 GAT layers ---
    int lda = 64;
    for (int l = 0; l < 5; ++l) {
        const int K = (l == 0) ? 64 : 256;
        const int NC = (l == 4) ? 40 : 256;
        dim3 ggrid(N_PAD / 128, (NC + 127) / 128);
        const _Float16* wl = wt + (size_t)l * 2 * 65536;
        if (l < 4) {
            gemm_mfma_kernel<1><<<ggrid, 256, 0, stream>>>(
                planes, PSTRIDE, lda, wl, Hb, K, NC, AS[l], AD[l], asn, adn);
            aggregate_kernel<64, 1><<<N_NODES, 256, 0, stream>>>(
                Hb, asn, adn, rowptr, col, BI[l], planes, PSTRIDE, nullptr);
        } else {
            gemm_mfma_kernel<0><<<ggrid, 256, 0, stream>>>(
                planes, PSTRIDE, lda, wl, Hb, K, NC, AS[l], AD[l], asn, adn);
            attn_coef_kernel<<<(N_NODES * HEADS + 255) / 256, 256, 0, stream>>>(
                Hb, AS[l], AD[l], asn, adn, 10);
            aggregate_kernel<10, 0><<<N_NODES, 256, 0, stream>>>(
                Hb, asn, adn, rowptr, col, BI[l], nullptr, 0, (float*)d_out);
        }
        lda = 256;
    }
    (void)in_sizes; (void)n_in; (void)out_size; (void)ws_size;
}

// Round 7
// 945.950 us; speedup vs baseline: 1.3308x; 1.0931x over previous
//
#include <hip/hip_runtime.h>
#include <hip/hip_bf16.h>
#include <math.h>

#define N_NODES 50000
#define N_PAD   50048   // 391 * 128
#define N_EDGES 800000
#define HEADS 4

typedef __attribute__((ext_vector_type(8))) _Float16 half8_t;
typedef __attribute__((ext_vector_type(4))) float f32x4;

// 2-way f16 split: v ~= (float)p0 + (float)p1, exact to ~2^-23 relative.
__device__ inline void split2(float v, _Float16& p0, _Float16& p1) {
    p0 = (_Float16)v;
    p1 = (_Float16)(v - (float)p0);
}

// ---------------------------------------------------------------------------
// CSR construction
// ---------------------------------------------------------------------------

__global__ void init_deg_kernel(int* __restrict__ deg) {
    int i = blockIdx.x * blockDim.x + threadIdx.x;
    if (i < N_NODES) deg[i] = 1;  // self-loop
}

__global__ void hist_kernel(const int* __restrict__ dst, int* __restrict__ deg) {
    int i = blockIdx.x * blockDim.x + threadIdx.x;
    if (i < N_EDGES) atomicAdd(&deg[dst[i]], 1);
}

// Wave-coalesced two-phase scan: 16 waves, each owns a contiguous chunk.
// Phase 1: coalesced wave totals. Phase 2: wave-parallel shfl prefix.
// deg may alias cursor (each wave reads only its own chunk, and within an
// iteration reads deg[i] before writing cursor[i]; later reads are at higher i).
__global__ __launch_bounds__(1024) void scan_kernel(const int* __restrict__ deg,
                                                    int* __restrict__ rowptr,
                                                    int* __restrict__ cursor) {
    __shared__ int wsums[16];
    const int t = threadIdx.x;
    const int wv = t >> 6, ln = t & 63;
    const int WCHUNK = (N_NODES + 15) / 16;   // 3125
    const int base = wv * WCHUNK;
    int lim = base + WCHUNK; if (lim > N_NODES) lim = N_NODES;

    int tot = 0;
    for (int i = base + ln; i < lim; i += 64) tot += deg[i];
#pragma unroll
    for (int o = 1; o < 64; o <<= 1) tot += __shfl_xor(tot, o);
    if (ln == 0) wsums[wv] = tot;
    __syncthreads();

    int run = 0;
    for (int w = 0; w < wv; ++w) run += wsums[w];

    for (int i0 = base; i0 < lim; i0 += 64) {
        int i = i0 + ln;
        int d = (i < lim) ? deg[i] : 0;
        int sc = d;
#pragma unroll
        for (int o = 1; o < 64; o <<= 1) {
            int v = __shfl_up(sc, o);
            if (ln >= o) sc += v;
        }
        if (i < lim) {
            int val = run + sc - d;
            rowptr[i] = val;
            cursor[i] = val;
        }
        run += __shfl(sc, 63);
    }
    if (t == 1023) rowptr[N_NODES] = run;
}

__global__ void scatter_kernel(const int* __restrict__ src, const int* __restrict__ dst,
                               int* __restrict__ cursor, int* __restrict__ col) {
    int i = blockIdx.x * blockDim.x + threadIdx.x;
    if (i < N_EDGES) {
        int d = dst[i];
        int pos = atomicAdd(&cursor[d], 1);
        col[pos] = src[i];
    } else if (i < N_EDGES + N_NODES) {
        int n = i - N_EDGES;
        int pos = atomicAdd(&cursor[n], 1);
        col[pos] = n;
    }
}

// ---------------------------------------------------------------------------
// Splitters (row-major planes)
// ---------------------------------------------------------------------------

__global__ void x_split_kernel(const float* __restrict__ x, _Float16* __restrict__ pl,
                               size_t pstride) {
    int i = blockIdx.x * blockDim.x + threadIdx.x;
    if (i >= N_NODES * 64) return;
    _Float16 a, b;
    split2(x[i], a, b);
    pl[i] = a;
    pl[pstride + i] = b;
}

__global__ void w_split_kernel(const float* __restrict__ W, _Float16* __restrict__ wt,
                               int K, int NC) {
    int t = blockIdx.x * blockDim.x + threadIdx.x;  // 65536 = 256 cols x 256 k
    int c = t >> 8, k = t & 255;
    float v = (k < K && c < NC) ? W[k * NC + c] : 0.f;
    _Float16 a, b;
    split2(v, a, b);
    wt[t] = a;           // Wt[col][k] row-major in col
    wt[65536 + t] = b;
}

// ---------------------------------------------------------------------------
// f16x2 MFMA GEMM, reg-prefetch pipelined; optional fused attn-coef epilogue
// (CH==64 layers: each 64-col wave quarter == exactly one head).
// Block 128x128, 4 waves (2x2 of 64x64), BK=32, mfma_f32_16x16x32_f16,
// 3 MFMAs per (i,j): a0b0 + a0b1 + a1b0  (a1b1 ~ 2^-22, dropped).
// ---------------------------------------------------------------------------

template <int FUSE_ATTN>
__global__ __launch_bounds__(256) void gemm_mfma_kernel(
        const _Float16* __restrict__ Apl, size_t apstride, int lda,
        const _Float16* __restrict__ Wt,   // [2][256 cols][256 k], zero-padded
        float* __restrict__ C, int K, int NC,
        const float* __restrict__ as_flat, const float* __restrict__ ad_flat,
        float* __restrict__ asn, float* __restrict__ adn) {
    __shared__ _Float16 As[2][128][40];   // stride 80B: 16B-aligned, 2-way banks
    __shared__ _Float16 Bs[2][128][40];

    const int tid = threadIdx.x;
    const int lane = tid & 63;
    const int wave = tid >> 6;
    const int wr = (wave >> 1) * 64;
    const int wc = (wave & 1) * 64;
    const int m0 = blockIdx.x * 128;
    const int n0 = blockIdx.y * 128;

    f32x4 acc[4][4];
#pragma unroll
    for (int i = 0; i < 4; ++i)
#pragma unroll
        for (int j = 0; j < 4; ++j) acc[i][j] = (f32x4){0.f, 0.f, 0.f, 0.f};

    const int row0 = tid >> 2, q = tid & 3;
    const int row1 = row0 + 64;

    const _Float16* aptr0 = Apl + (size_t)(m0 + row0) * lda + q * 8;
    const _Float16* aptr1 = Apl + (size_t)(m0 + row1) * lda + q * 8;
    const _Float16* bptr0 = Wt + (size_t)(n0 + row0) * 256 + q * 8;
    const _Float16* bptr1 = Wt + (size_t)(n0 + row1) * 256 + q * 8;

    half8_t pa[2][2], pb[2][2];
#pragma unroll
    for (int p = 0; p < 2; ++p) {
        pa[p][0] = *(const half8_t*)(aptr0 + p * apstride);
        pa[p][1] = *(const half8_t*)(aptr1 + p * apstride);
        pb[p][0] = *(const half8_t*)(bptr0 + p * 65536);
        pb[p][1] = *(const half8_t*)(bptr1 + p * 65536);
    }

    for (int k0 = 0; k0 < K; k0 += 32) {
        if (k0) __syncthreads();   // prev-iter LDS readers done
#pragma unroll
        for (int p = 0; p < 2; ++p) {
            *(half8_t*)(&As[p][row0][q * 8]) = pa[p][0];
            *(half8_t*)(&As[p][row1][q * 8]) = pa[p][1];
            *(half8_t*)(&Bs[p][row0][q * 8]) = pb[p][0];
            *(half8_t*)(&Bs[p][row1][q * 8]) = pb[p][1];
        }
        __syncthreads();

        // issue next-tile global loads early: latency hides under ds_read+MFMA
        if (k0 + 32 < K) {
            int kn = k0 + 32;
#pragma unroll
            for (int p = 0; p < 2; ++p) {
                pa[p][0] = *(const half8_t*)(aptr0 + p * apstride + kn);
                pa[p][1] = *(const half8_t*)(aptr1 + p * apstride + kn);
                pb[p][0] = *(const half8_t*)(bptr0 + p * 65536 + kn);
                pb[p][1] = *(const half8_t*)(bptr1 + p * 65536 + kn);
            }
        }

        half8_t bf[2][4];
#pragma unroll
        for (int p = 0; p < 2; ++p)
#pragma unroll
            for (int j = 0; j < 4; ++j)
                bf[p][j] = *(const half8_t*)(&Bs[p][wc + j * 16 + (lane & 15)][(lane >> 4) * 8]);

#pragma unroll
        for (int i = 0; i < 4; ++i) {
            half8_t af0 = *(const half8_t*)(&As[0][wr + i * 16 + (lane & 15)][(lane >> 4) * 8]);
            half8_t af1 = *(const half8_t*)(&As[1][wr + i * 16 + (lane & 15)][(lane >> 4) * 8]);
#pragma unroll
            for (int j = 0; j < 4; ++j) {
                f32x4 c = acc[i][j];
                c = __builtin_amdgcn_mfma_f32_16x16x32_f16(af0, bf[1][j], c, 0, 0, 0);
                c = __builtin_amdgcn_mfma_f32_16x16x32_f16(af1, bf[0][j], c, 0, 0, 0);
                c = __builtin_amdgcn_mfma_f32_16x16x32_f16(af0, bf[0][j], c, 0, 0, 0);
                acc[i][j] = c;
            }
        }
    }

    // epilogue: C/D mapping col = lane&15, row = (lane>>4)*4 + reg
    const int rbase = m0 + wr + (lane >> 4) * 4;
    const int cbase = n0 + wc + (lane & 15);
#pragma unroll
    for (int i = 0; i < 4; ++i)
#pragma unroll
        for (int j = 0; j < 4; ++j) {
            int gcol = cbase + j * 16;
            if (gcol >= NC) continue;
#pragma unroll
            for (int r4 = 0; r4 < 4; ++r4) {
                int grow = rbase + i * 16 + r4;
                if (grow < N_NODES) C[(size_t)grow * NC + gcol] = acc[i][j][r4];
            }
        }

    if (FUSE_ATTN) {
        // this wave's 64 cols == head (n0+wc)>>6 (CH=64)
        const int hd_out = (n0 + wc) >> 6;
        float as_v[4], ad_v[4];
#pragma unroll
        for (int j = 0; j < 4; ++j) {
            int gc = cbase + j * 16;
            as_v[j] = as_flat[gc];
            ad_v[j] = ad_flat[gc];
        }
#pragma unroll
        for (int i = 0; i < 4; ++i)
#pragma unroll
            for (int r4 = 0; r4 < 4; ++r4) {
                float ps = 0.f, pd = 0.f;
#pragma unroll
                for (int j = 0; j < 4; ++j) {
                    float v = acc[i][j][r4];
                    ps += v * as_v[j];
                    pd += v * ad_v[j];
                }
#pragma unroll
                for (int o = 1; o < 16; o <<= 1) {
                    ps += __shfl_xor(ps, o);
                    pd += __shfl_xor(pd, o);
                }
                if ((lane & 15) == 0) {
                    int grow = rbase + i * 16 + r4;
                    if (grow < N_NODES) {
                        asn[grow * 4 + hd_out] = ps;
                        adn[grow * 4 + hd_out] = pd;
                    }
                }
            }
    }
}

// ---------------------------------------------------------------------------
// Standalone attention coefficients (layer 4 only, CH=10)
// ---------------------------------------------------------------------------

__global__ void attn_coef_kernel(const float* __restrict__ h,
                                 const float* __restrict__ a_s,
                                 const float* __restrict__ a_d,
                                 float* __restrict__ asn, float* __restrict__ adn,
                                 int CH) {
    int t = blockIdx.x * blockDim.x + threadIdx.x;
    if (t >= N_NODES * HEADS) return;
    int n = t >> 2;
    int hd = t & 3;
    const float* hp = h + (size_t)n * HEADS * CH + hd * CH;
    const float* sp = a_s + hd * CH;
    const float* dp = a_d + hd * CH;
    float s1 = 0.f, s2 = 0.f;
    for (int c = 0; c < CH; c += 2) {
        float2 hv = *reinterpret_cast<const float2*>(&hp[c]);
        float2 av = *reinterpret_cast<const float2*>(&sp[c]);
        float2 dv = *reinterpret_cast<const float2*>(&dp[c]);
        s1 += hv.x * av.x + hv.y * av.y;
        s2 += hv.x * dv.x + hv.y * dv.y;
    }
    asn[t] = s1;
    adn[t] = s2;
}

// ---------------------------------------------------------------------------
// Batched online-softmax aggregation with 8-deep gather ILP.
// EMIT=1 -> write 2 f16 planes (row-major).
// ---------------------------------------------------------------------------

template <int CH, int EMIT>
__global__ __launch_bounds__(256) void aggregate_kernel(
        const float* __restrict__ h, const float* __restrict__ asn,
        const float* __restrict__ adn, const int* __restrict__ rowptr,
        const int* __restrict__ col, const float* __restrict__ bias,
        _Float16* __restrict__ pl, size_t pstride, float* __restrict__ out) {
    constexpr int HC = HEADS * CH;
    __shared__ float2 pair_lds[HEADS][32];

    const int n = blockIdx.x;
    const int hd = threadIdx.x >> 6;
    const int lane = threadIdx.x & 63;
    const int el = lane & 31;
    const int hdoff = hd * CH + lane;

    const int start = rowptr[n];
    const int end = rowptr[n + 1];
    const float adv = adn[(n << 2) | hd];

    float m = -INFINITY, s = 0.f;
    float accv[4] = {0.f, 0.f, 0.f, 0.f};

    for (int e0 = start; e0 < end; e0 += 32) {
        int e = e0 + el;
        bool valid = (lane < 32) && (e < end);
        int srcl = n;
        float ev = -INFINITY;
        if (valid) {
            srcl = col[e];
            float t = asn[(srcl << 2) | hd] + adv;
            ev = (t > 0.f) ? t : 0.2f * t;
        }
        float bm = ev;
#pragma unroll
        for (int o = 1; o < 64; o <<= 1) bm = fmaxf(bm, __shfl_xor(bm, o));
        float mn = fmaxf(m, bm);
        float scale = __expf(m - mn);
        float p = __expf(ev - mn);        // invalid lanes -> 0
        float ps = p;
#pragma unroll
        for (int o = 1; o < 64; o <<= 1) ps += __shfl_xor(ps, o);
        s = s * scale + ps;
#pragma unroll
        for (int c = 0; c < 4; ++c) accv[c] *= scale;
        m = mn;

        if (lane < 32) pair_lds[hd][lane] = make_float2(__int_as_float(srcl), p);
        // same-wave LDS write->read: compiler inserts lgkmcnt

        int cnt = end - e0; if (cnt > 32) cnt = 32;
        int cnt8 = (cnt + 7) & ~7;
        for (int i0 = 0; i0 < cnt8; i0 += 8) {
            int sv[8]; float pv[8];
#pragma unroll
            for (int j = 0; j < 8; ++j) {
                float2 pr = pair_lds[hd][i0 + j];
                sv[j] = __float_as_int(pr.x);
                pv[j] = pr.y;
            }
            float hv[8];
#pragma unroll
            for (int j = 0; j < 8; ++j)
                hv[j] = (lane < CH) ? h[(size_t)sv[j] * HC + hdoff] : 0.f;
#pragma unroll
            for (int j = 0; j < 8; ++j) accv[j & 3] += pv[j] * hv[j];
        }
    }

    if (lane < CH) {
        float acc = (accv[0] + accv[1]) + (accv[2] + accv[3]);
        float v = acc / (s + 1e-16f) + bias[hd * CH + lane];
        v = fmaxf(v, 0.f);
        if (EMIT) {
            _Float16 a, b;
            split2(v, a, b);
            size_t off = (size_t)n * HC + hd * CH + lane;
            pl[off] = a;
            pl[pstride + off] = b;
        } else {
            out[n * HC + hd * CH + lane] = v;
        }
    }
}

// ---------------------------------------------------------------------------

extern "C" void kernel_launch(void* const* d_in, const int* in_sizes, int n_in,
                              void* d_out, int out_size, void* d_ws, size_t ws_size,
                              hipStream_t stream) {
    const float* x_in = (const float*)d_in[0];
    const int* ei = (const int*)d_in[1];
    const int* src = ei;
    const int* dst = ei + N_EDGES;

    const float *W[5], *AS[5], *AD[5], *BI[5];
    for (int l = 0; l < 5; ++l) {
        W[l]  = (const float*)d_in[2 + l * 4 + 0];
        AS[l] = (const float*)d_in[2 + l * 4 + 1];
        AD[l] = (const float*)d_in[2 + l * 4 + 2];
        BI[l] = (const float*)d_in[2 + l * 4 + 3];
    }

    // workspace carve-up
    const size_t PSTRIDE = (size_t)N_PAD * 256;           // elements per plane
    _Float16* planes = (_Float16*)d_ws;                   // 2 f16 planes
    float* Hb   = (float*)(planes + 2 * PSTRIDE);         // N x 256 f32
    float* asn  = Hb + (size_t)N_NODES * 256;
    float* adn  = asn + (size_t)N_NODES * HEADS;
    int* rowptr = (int*)(adn + (size_t)N_NODES * HEADS);  // N+1
    int* cursor = rowptr + (N_NODES + 1);
    int* col    = cursor + N_NODES;                       // E + N
    _Float16* wt = (_Float16*)(((uintptr_t)(col + N_EDGES + N_NODES) + 15) & ~(uintptr_t)15);

    // --- CSR build ---
    init_deg_kernel<<<(N_NODES + 255) / 256, 256, 0, stream>>>(cursor);
    hist_kernel<<<(N_EDGES + 255) / 256, 256, 0, stream>>>(dst, cursor);
    scan_kernel<<<1, 1024, 0, stream>>>(cursor, rowptr, cursor);
    scatter_kernel<<<(N_EDGES + N_NODES + 255) / 256, 256, 0, stream>>>(src, dst, cursor, col);

    // --- weight & input splits ---
    for (int l = 0; l < 5; ++l) {
        int Kl = (l == 0) ? 64 : 256;
        int NCl = (l == 4) ? 40 : 256;
        w_split_kernel<<<256, 256, 0, stream>>>(W[l], wt + (size_t)l * 2 * 65536, Kl, NCl);
    }
    x_split_kernel<<<(N_NODES * 64 + 255) / 256, 256, 0, stream>>>(x_in, planes, PSTRIDE);

    // --- 5 GAT layers ---
    int lda = 64;
    for (int l = 0; l < 5; ++l) {
        const int K = (l == 0) ? 64 : 256;
        const int NC = (l == 4) ? 40 : 256;
        dim3 ggrid(N_PAD / 128, (NC + 127) / 128);
        const _Float16* wl = wt + (size_t)l * 2 * 65536;
        if (l < 4) {
            gemm_mfma_kernel<1><<<ggrid, 256, 0, stream>>>(
                planes, PSTRIDE, lda, wl, Hb, K, NC, AS[l], AD[l], asn, adn);
            aggregate_kernel<64, 1><<<N_NODES, 256, 0, stream>>>(
                Hb, asn, adn, rowptr, col, BI[l], planes, PSTRIDE, nullptr);
        } else {
            gemm_mfma_kernel<0><<<ggrid, 256, 0, stream>>>(
                planes, PSTRIDE, lda, wl, Hb, K, NC, AS[l], AD[l], asn, adn);
            attn_coef_kernel<<<(N_NODES * HEADS + 255) / 256, 256, 0, stream>>>(
                Hb, AS[l], AD[l], asn, adn, 10);
            aggregate_kernel<10, 0><<<N_NODES, 256, 0, stream>>>(
                Hb, asn, adn, rowptr, col, BI[l], nullptr, 0, (float*)d_out);
        }
        lda = 256;
    }
    (void)in_sizes; (void)n_in; (void)out_size; (void)ws_size;
}

// Round 9
// 933.338 us; speedup vs baseline: 1.3487x; 1.0135x over previous
//
#include <hip/hip_runtime.h>
#include <hip/hip_bf16.h>
#include <math.h>

#define N_NODES 50000
#define N_PAD   50048   // 391 * 128
#define N_EDGES 800000
#define HEADS 4

typedef __attribute__((ext_vector_type(8))) _Float16 half8_t;
typedef __attribute__((ext_vector_type(4))) _Float16 half4_t;
typedef __attribute__((ext_vector_type(4))) float f32x4;

// 2-way f16 split: v ~= (float)p0 + (float)p1, exact to ~2^-23 relative.
__device__ inline void split2(float v, _Float16& p0, _Float16& p1) {
    p0 = (_Float16)v;
    p1 = (_Float16)(v - (float)p0);
}

// ---------------------------------------------------------------------------
// CSR construction
// ---------------------------------------------------------------------------

__global__ void init_deg_kernel(int* __restrict__ deg) {
    int i = blockIdx.x * blockDim.x + threadIdx.x;
    if (i < N_NODES) deg[i] = 1;  // self-loop
}

__global__ void hist_kernel(const int* __restrict__ dst, int* __restrict__ deg) {
    int i = blockIdx.x * blockDim.x + threadIdx.x;
    if (i < N_EDGES) atomicAdd(&deg[dst[i]], 1);
}

// Wave-coalesced two-phase scan (16 waves, contiguous chunks).
__global__ __launch_bounds__(1024) void scan_kernel(const int* __restrict__ deg,
                                                    int* __restrict__ rowptr,
                                                    int* __restrict__ cursor) {
    __shared__ int wsums[16];
    const int t = threadIdx.x;
    const int wv = t >> 6, ln = t & 63;
    const int WCHUNK = (N_NODES + 15) / 16;   // 3125
    const int base = wv * WCHUNK;
    int lim = base + WCHUNK; if (lim > N_NODES) lim = N_NODES;

    int tot = 0;
    for (int i = base + ln; i < lim; i += 64) tot += deg[i];
#pragma unroll
    for (int o = 1; o < 64; o <<= 1) tot += __shfl_xor(tot, o);
    if (ln == 0) wsums[wv] = tot;
    __syncthreads();

    int run = 0;
    for (int w = 0; w < wv; ++w) run += wsums[w];

    for (int i0 = base; i0 < lim; i0 += 64) {
        int i = i0 + ln;
        int d = (i < lim) ? deg[i] : 0;
        int sc = d;
#pragma unroll
        for (int o = 1; o < 64; o <<= 1) {
            int v = __shfl_up(sc, o);
            if (ln >= o) sc += v;
        }
        if (i < lim) {
            int val = run + sc - d;
            rowptr[i] = val;
            cursor[i] = val;
        }
        run += __shfl(sc, 63);
    }
    if (t == 1023) rowptr[N_NODES] = run;
}

__global__ void scatter_kernel(const int* __restrict__ src, const int* __restrict__ dst,
                               int* __restrict__ cursor, int* __restrict__ col) {
    int i = blockIdx.x * blockDim.x + threadIdx.x;
    if (i < N_EDGES) {
        int d = dst[i];
        int pos = atomicAdd(&cursor[d], 1);
        col[pos] = src[i];
    } else if (i < N_EDGES + N_NODES) {
        int n = i - N_EDGES;
        int pos = atomicAdd(&cursor[n], 1);
        col[pos] = n;
    }
}

// ---------------------------------------------------------------------------
// Splitters (row-major planes)
// ---------------------------------------------------------------------------

__global__ void x_split_kernel(const float* __restrict__ x, _Float16* __restrict__ pl,
                               size_t pstride) {
    int i = blockIdx.x * blockDim.x + threadIdx.x;
    if (i >= N_NODES * 64) return;
    _Float16 a, b;
    split2(x[i], a, b);
    pl[i] = a;
    pl[pstride + i] = b;
}

__global__ void w_split_kernel(const float* __restrict__ W, _Float16* __restrict__ wt,
                               int K, int NC) {
    int t = blockIdx.x * blockDim.x + threadIdx.x;  // 65536 = 256 cols x 256 k
    int c = t >> 8, k = t & 255;
    float v = (k < K && c < NC) ? W[k * NC + c] : 0.f;
    _Float16 a, b;
    split2(v, a, b);
    wt[t] = a;           // Wt[col][k] row-major in col
    wt[65536 + t] = b;
}

// ---------------------------------------------------------------------------
// f16x2 MFMA GEMM, reg-prefetch pipelined.
// FUSE_ATTN=1 (layers 0-3): emit h as 2 f16 planes + fused asn/adn epilogue.
// FUSE_ATTN=0 (layer 4):   write f32 C.
// Block 128x128, 4 waves (2x2 of 64x64), BK=32, mfma_f32_16x16x32_f16,
// 3 MFMAs per (i,j): a0b0 + a0b1 + a1b0  (a1b1 ~ 2^-22, dropped).
// ---------------------------------------------------------------------------

template <int FUSE_ATTN>
__global__ __launch_bounds__(256) void gemm_mfma_kernel(
        const _Float16* __restrict__ Apl, size_t apstride, int lda,
        const _Float16* __restrict__ Wt,   // [2][256 cols][256 k], zero-padded
        _Float16* __restrict__ hpl, size_t hstride,
        float* __restrict__ C, int K, int NC,
        const float* __restrict__ as_flat, const float* __restrict__ ad_flat,
        float* __restrict__ asn, float* __restrict__ adn) {
    __shared__ _Float16 As[2][128][40];   // stride 80B: 16B-aligned, 2-way banks
    __shared__ _Float16 Bs[2][128][40];

    const int tid = threadIdx.x;
    const int lane = tid & 63;
    const int wave = tid >> 6;
    const int wr = (wave >> 1) * 64;
    const int wc = (wave & 1) * 64;
    const int m0 = blockIdx.x * 128;
    const int n0 = blockIdx.y * 128;

    f32x4 acc[4][4];
#pragma unroll
    for (int i = 0; i < 4; ++i)
#pragma unroll
        for (int j = 0; j < 4; ++j) acc[i][j] = (f32x4){0.f, 0.f, 0.f, 0.f};

    const int row0 = tid >> 2, q = tid & 3;
    const int row1 = row0 + 64;

    const _Float16* aptr0 = Apl + (size_t)(m0 + row0) * lda + q * 8;
    const _Float16* aptr1 = Apl + (size_t)(m0 + row1) * lda + q * 8;
    const _Float16* bptr0 = Wt + (size_t)(n0 + row0) * 256 + q * 8;
    const _Float16* bptr1 = Wt + (size_t)(n0 + row1) * 256 + q * 8;

    half8_t pa[2][2], pb[2][2];
#pragma unroll
    for (int p = 0; p < 2; ++p) {
        pa[p][0] = *(const half8_t*)(aptr0 + p * apstride);
        pa[p][1] = *(const half8_t*)(aptr1 + p * apstride);
        pb[p][0] = *(const half8_t*)(bptr0 + p * 65536);
        pb[p][1] = *(const half8_t*)(bptr1 + p * 65536);
    }

    for (int k0 = 0; k0 < K; k0 += 32) {
        if (k0) __syncthreads();   // prev-iter LDS readers done
#pragma unroll
        for (int p = 0; p < 2; ++p) {
            *(half8_t*)(&As[p][row0][q * 8]) = pa[p][0];
            *(half8_t*)(&As[p][row1][q * 8]) = pa[p][1];
            *(half8_t*)(&Bs[p][row0][q * 8]) = pb[p][0];
            *(half8_t*)(&Bs[p][row1][q * 8]) = pb[p][1];
        }
        __syncthreads();

        // issue next-tile global loads early: latency hides under ds_read+MFMA
        if (k0 + 32 < K) {
            int kn = k0 + 32;
#pragma unroll
            for (int p = 0; p < 2; ++p) {
                pa[p][0] = *(const half8_t*)(aptr0 + p * apstride + kn);
                pa[p][1] = *(const half8_t*)(aptr1 + p * apstride + kn);
                pb[p][0] = *(const half8_t*)(bptr0 + p * 65536 + kn);
                pb[p][1] = *(const half8_t*)(bptr1 + p * 65536 + kn);
            }
        }

        half8_t bf[2][4];
#pragma unroll
        for (int p = 0; p < 2; ++p)
#pragma unroll
            for (int j = 0; j < 4; ++j)
                bf[p][j] = *(const half8_t*)(&Bs[p][wc + j * 16 + (lane & 15)][(lane >> 4) * 8]);

#pragma unroll
        for (int i = 0; i < 4; ++i) {
            half8_t af0 = *(const half8_t*)(&As[0][wr + i * 16 + (lane & 15)][(lane >> 4) * 8]);
            half8_t af1 = *(const half8_t*)(&As[1][wr + i * 16 + (lane & 15)][(lane >> 4) * 8]);
#pragma unroll
            for (int j = 0; j < 4; ++j) {
                f32x4 c = acc[i][j];
                c = __builtin_amdgcn_mfma_f32_16x16x32_f16(af0, bf[1][j], c, 0, 0, 0);
                c = __builtin_amdgcn_mfma_f32_16x16x32_f16(af1, bf[0][j], c, 0, 0, 0);
                c = __builtin_amdgcn_mfma_f32_16x16x32_f16(af0, bf[0][j], c, 0, 0, 0);
                acc[i][j] = c;
            }
        }
    }

    // epilogue: C/D mapping col = lane&15, row = (lane>>4)*4 + reg
    const int rbase = m0 + wr + (lane >> 4) * 4;
    const int cbase = n0 + wc + (lane & 15);

    if (FUSE_ATTN) {
        // h -> 2 f16 planes (NC == 256)
#pragma unroll
        for (int i = 0; i < 4; ++i)
#pragma unroll
            for (int j = 0; j < 4; ++j) {
                int gcol = cbase + j * 16;
#pragma unroll
                for (int r4 = 0; r4 < 4; ++r4) {
                    int grow = rbase + i * 16 + r4;
                    if (grow < N_NODES) {
                        _Float16 a, b;
                        split2(acc[i][j][r4], a, b);
                        size_t off = (size_t)grow * 256 + gcol;
                        hpl[off] = a;
                        hpl[hstride + off] = b;
                    }
                }
            }
        // fused asn/adn: this wave's 64 cols == head (n0+wc)>>6 (CH=64)
        const int hd_out = (n0 + wc) >> 6;
        float as_v[4], ad_v[4];
#pragma unroll
        for (int j = 0; j < 4; ++j) {
            int gc = cbase + j * 16;
            as_v[j] = as_flat[gc];
            ad_v[j] = ad_flat[gc];
        }
#pragma unroll
        for (int i = 0; i < 4; ++i)
#pragma unroll
            for (int r4 = 0; r4 < 4; ++r4) {
                float ps = 0.f, pd = 0.f;
#pragma unroll
                for (int j = 0; j < 4; ++j) {
                    float v = acc[i][j][r4];
                    ps += v * as_v[j];
                    pd += v * ad_v[j];
                }
#pragma unroll
                for (int o = 1; o < 16; o <<= 1) {
                    ps += __shfl_xor(ps, o);
                    pd += __shfl_xor(pd, o);
                }
                if ((lane & 15) == 0) {
                    int grow = rbase + i * 16 + r4;
                    if (grow < N_NODES) {
                        asn[grow * 4 + hd_out] = ps;
                        adn[grow * 4 + hd_out] = pd;
                    }
                }
            }
    } else {
#pragma unroll
        for (int i = 0; i < 4; ++i)
#pragma unroll
            for (int j = 0; j < 4; ++j) {
                int gcol = cbase + j * 16;
                if (gcol >= NC) continue;
#pragma unroll
                for (int r4 = 0; r4 < 4; ++r4) {
                    int grow = rbase + i * 16 + r4;
                    if (grow < N_NODES) C[(size_t)grow * NC + gcol] = acc[i][j][r4];
                }
            }
    }
}

// ---------------------------------------------------------------------------
// Standalone attention coefficients (layer 4 only, CH=10)
// ---------------------------------------------------------------------------

__global__ void attn_coef_kernel(const float* __restrict__ h,
                                 const float* __restrict__ a_s,
                                 const float* __restrict__ a_d,
                                 float* __restrict__ asn, float* __restrict__ adn,
                                 int CH) {
    int t = blockIdx.x * blockDim.x + threadIdx.x;
    if (t >= N_NODES * HEADS) return;
    int n = t >> 2;
    int hd = t & 3;
    const float* hp = h + (size_t)n * HEADS * CH + hd * CH;
    const float* sp = a_s + hd * CH;
    const float* dp = a_d + hd * CH;
    float s1 = 0.f, s2 = 0.f;
    for (int c = 0; c < CH; c += 2) {
        float2 hv = *reinterpret_cast<const float2*>(&hp[c]);
        float2 av = *reinterpret_cast<const float2*>(&sp[c]);
        float2 dv = *reinterpret_cast<const float2*>(&dp[c]);
        s1 += hv.x * av.x + hv.y * av.y;
        s2 += hv.x * dv.x + hv.y * dv.y;
    }
    asn[t] = s1;
    adn[t] = s2;
}

// ---------------------------------------------------------------------------
// One-wave-per-node aggregation (CH=64 layers): lane = (head, 4-ch block),
// whole 256-col row gathered as one coalesced wave read from 2 f16 planes.
// Per-head softmax state in 16-lane groups; p/src broadcast via shfl.
// Emits 2 f16 planes (next layer's GEMM input).
// ---------------------------------------------------------------------------

__global__ __launch_bounds__(256) void aggregate64_kernel(
        const _Float16* __restrict__ hpl, size_t hstride,
        const float* __restrict__ asn, const float* __restrict__ adn,
        const int* __restrict__ rowptr, const int* __restrict__ col,
        const float* __restrict__ bias,
        _Float16* __restrict__ pl, size_t pstride) {
    const int n = (blockIdx.x << 2) + (threadIdx.x >> 6);
    const int lane = threadIdx.x & 63;
    const int hd = lane >> 4;        // this lane's head (both for p and channels)
    const int e16 = lane & 15;
    const int pbase = lane & 48;

    const int start = rowptr[n];
    const int end = rowptr[n + 1];
    const float adv = adn[(n << 2) | hd];

    float m = -INFINITY, s = 0.f;
    float a0 = 0.f, a1 = 0.f, a2 = 0.f, a3 = 0.f;

    for (int e0 = start; e0 < end; e0 += 16) {
        int e = e0 + e16;
        int srcl = n;
        float ev = -INFINITY;
        if (e < end) {
            srcl = col[e];
            float t = asn[(srcl << 2) | hd] + adv;
            ev = (t > 0.f) ? t : 0.2f * t;   // leaky_relu(0.2)
        }
        // per-head (16-lane group) batch max
        float bm = ev;
#pragma unroll
        for (int o = 1; o < 16; o <<= 1) bm = fmaxf(bm, __shfl_xor(bm, o));
        float mn = fmaxf(m, bm);
        float scale = __expf(m - mn);        // first batch: exp(-inf)=0
        float p = __expf(ev - mn);           // invalid lanes -> 0
        float ps = p;
#pragma unroll
        for (int o = 1; o < 16; o <<= 1) ps += __shfl_xor(ps, o);
        s = s * scale + ps;
        a0 *= scale; a1 *= scale; a2 *= scale; a3 *= scale;
        m = mn;

        int cnt = end - e0; if (cnt > 16) cnt = 16;
        int cnt4 = (cnt + 3) & ~3;
        for (int j0 = 0; j0 < cnt4; j0 += 4) {
            int sj[4]; float pj[4];
#pragma unroll
            for (int j = 0; j < 4; ++j) {
                sj[j] = __shfl(srcl, j0 + j);            // edge j's src row
                pj[j] = __shfl(p, pbase + j0 + j);       // p[edge j, my head]
            }
            half4_t h0[4], h1[4];
#pragma unroll
            for (int j = 0; j < 4; ++j) {
                const _Float16* hp = hpl + (size_t)sj[j] * 256 + (lane << 2);
                h0[j] = *(const half4_t*)hp;
                h1[j] = *(const half4_t*)(hp + hstride);
            }
#pragma unroll
            for (int j = 0; j < 4; ++j) {
                a0 += pj[j] * ((float)h0[j][0] + (float)h1[j][0]);
                a1 += pj[j] * ((float)h0[j][1] + (float)h1[j][1]);
                a2 += pj[j] * ((float)h0[j][2] + (float)h1[j][2]);
                a3 += pj[j] * ((float)h0[j][3] + (float)h1[j][3]);
            }
        }
    }

    float sd = s + 1e-16f;
    const float* bp = bias + (lane << 2);
    float v0 = fmaxf(a0 / sd + bp[0], 0.f);
    float v1 = fmaxf(a1 / sd + bp[1], 0.f);
    float v2 = fmaxf(a2 / sd + bp[2], 0.f);
    float v3 = fmaxf(a3 / sd + bp[3], 0.f);

    _Float16 s0a, s0b, s1a, s1b, s2a, s2b, s3a, s3b;
    split2(v0, s0a, s0b);
    split2(v1, s1a, s1b);
    split2(v2, s2a, s2b);
    split2(v3, s3a, s3b);
    half4_t o0, o1;
    o0[0] = s0a; o0[1] = s1a; o0[2] = s2a; o0[3] = s3a;
    o1[0] = s0b; o1[1] = s1b; o1[2] = s2b; o1[3] = s3b;
    size_t off = (size_t)n * 256 + (lane << 2);
    *(half4_t*)(pl + off) = o0;
    *(half4_t*)(pl + pstride + off) = o1;
}

// ---------------------------------------------------------------------------
// Layer-4 aggregation (CH=10), f32 h, writes d_out. 4 waves/node as before.
// ---------------------------------------------------------------------------

template <int CH>
__global__ __launch_bounds__(256) void aggregate_out_kernel(
        const float* __restrict__ h, const float* __restrict__ asn,
        const float* __restrict__ adn, const int* __restrict__ rowptr,
        const int* __restrict__ col, const float* __restrict__ bias,
        float* __restrict__ out) {
    constexpr int HC = HEADS * CH;
    __shared__ float2 pair_lds[HEADS][32];

    const int n = blockIdx.x;
    const int hd = threadIdx.x >> 6;
    const int lane = threadIdx.x & 63;
    const int el = lane & 31;
    const int hdoff = hd * CH + lane;

    const int start = rowptr[n];
    const int end = rowptr[n + 1];
    const float adv = adn[(n << 2) | hd];

    float m = -INFINITY, s = 0.f;
    float accv[4] = {0.f, 0.f, 0.f, 0.f};

    for (int e0 = start; e0 < end; e0 += 32) {
        int e = e0 + el;
        bool valid = (lane < 32) && (e < end);
        int srcl = n;
        float ev = -INFINITY;
        if (valid) {
            srcl = col[e];
            float t = asn[(srcl << 2) | hd] + adv;
            ev = (t > 0.f) ? t : 0.2f * t;
        }
        float bm = ev;
#pragma unroll
        for (int o = 1; o < 64; o <<= 1) bm = fmaxf(bm, __shfl_xor(bm, o));
        float mn = fmaxf(m, bm);
        float scale = __expf(m - mn);
        float p = __expf(ev - mn);
        float ps = p;
#pragma unroll
        for (int o = 1; o < 64; o <<= 1) ps += __shfl_xor(ps, o);
        s = s * scale + ps;
#pragma unroll
        for (int c = 0; c < 4; ++c) accv[c] *= scale;
        m = mn;

        if (lane < 32) pair_lds[hd][lane] = make_float2(__int_as_float(srcl), p);

        int cnt = end - e0; if (cnt > 32) cnt = 32;
        int cnt8 = (cnt + 7) & ~7;
        for (int i0 = 0; i0 < cnt8; i0 += 8) {
            int sv[8]; float pv[8];
#pragma unroll
            for (int j = 0; j < 8; ++j) {
                float2 pr = pair_lds[hd][i0 + j];
                sv[j] = __float_as_int(pr.x);
                pv[j] = pr.y;
            }
            float hv[8];
#pragma unroll
            for (int j = 0; j < 8; ++j)
                hv[j] = (lane < CH) ? h[(size_t)sv[j] * HC + hdoff] : 0.f;
#pragma unroll
            for (int j = 0; j < 8; ++j) accv[j & 3] += pv[j] * hv[j];
        }
    }

    if (lane < CH) {
        float acc = (accv[0] + accv[1]) + (accv[2] + accv[3]);
        float v = acc / (s + 1e-16f) + bias[hd * CH + lane];
        out[n * HC + hd * CH + lane] = fmaxf(v, 0.f);
    }
}

// ---------------------------------------------------------------------------

extern "C" void kernel_launch(void* const* d_in, const int* in_sizes, int n_in,
                              void* d_out, int out_size, void* d_ws, size_t ws_size,
                              hipStream_t stream) {
    const float* x_in = (const float*)d_in[0];
    const int* ei = (const int*)d_in[1];
    const int* src = ei;
    const int* dst = ei + N_EDGES;

    const float *W[5], *AS[5], *AD[5], *BI[5];
    for (int l = 0; l < 5; ++l) {
        W[l]  = (const float*)d_in[2 + l * 4 + 0];
        AS[l] = (const float*)d_in[2 + l * 4 + 1];
        AD[l] = (const float*)d_in[2 + l * 4 + 2];
        BI[l] = (const float*)d_in[2 + l * 4 + 3];
    }

    // workspace carve-up
    const size_t PSTRIDE = (size_t)N_PAD * 256;           // elements per plane
    _Float16* planes = (_Float16*)d_ws;                   // GEMM input planes (2)
    _Float16* hpl = planes + 2 * PSTRIDE;                 // GEMM h output planes (2)
    float* Hb   = (float*)(hpl + 2 * PSTRIDE);            // N x 40 f32 (layer 4)
    float* asn  = Hb + (size_t)N_NODES * 40;
    float* adn  = asn + (size_t)N_NODES * HEADS;
    int* rowptr = (int*)(adn + (size_t)N_NODES * HEADS);  // N+1
    int* cursor = rowptr + (N_NODES + 1);
    int* col    = cursor + N_NODES;                       // E + N
    _Float16* wt = (_Float16*)(((uintptr_t)(col + N_EDGES + N_NODES) + 15) & ~(uintptr_t)15);

    // --- CSR build ---
    init_deg_kernel<<<(N_NODES + 255) / 256, 256, 0, stream>>>(cursor);
    hist_kernel<<<(N_EDGES + 255) / 256, 256, 0, stream>>>(dst, cursor);
    scan_kernel<<<1, 1024, 0, stream>>>(cursor, rowptr, cursor);
    scatter_kernel<<<(N_EDGES + N_NODES + 255) / 256, 256, 0, stream>>>(src, dst, cursor, col);

    // --- weight & input splits ---
    for (int l = 0; l < 5; ++l) {
        int Kl = (l == 0) ? 64 : 256;
        int NCl = (l == 4) ? 40 : 256;
        w_split_kernel<<<256, 256, 0, stream>>>(W[l], wt + (size_t)l * 2 * 65536, Kl, NCl);
    }
    x_split_kernel<<<(N_NODES * 64 + 255) / 256, 256, 0, stream>>>(x_in, planes, PSTRIDE);

    // --- 5 GAT layers ---
    int lda = 64;
    for (int l = 0; l < 5; ++l) {
        const int K = (l == 0) ? 64 : 256;
        const int NC = (l == 4) ? 40 : 256;
        dim3 ggrid(N_PAD / 128, (NC + 127) / 128);
        const _Float16* wl = wt + (size_t)l * 2 * 65536;
        if (l < 4) {
            gemm_mfma_kernel<1><<<ggrid, 256, 0, stream>>>(
                planes, PSTRIDE, lda, wl, hpl, PSTRIDE, nullptr, K, NC,
                AS[l], AD[l], asn, adn);
            aggregate64_kernel<<<N_NODES / 4, 256, 0, stream>>>(
                hpl, PSTRIDE, asn, adn, rowptr, col, BI[l], planes, PSTRIDE);
        } else {
            gemm_mfma_kernel<0><<<ggrid, 256, 0, stream>>>(
                planes, PSTRIDE, lda, wl, nullptr, 0, Hb, K, NC,
                AS[l], AD[l], asn, adn);
            attn_coef_kernel<<<(N_NODES * HEADS + 255) / 256, 256, 0, stream>>>(
                Hb, AS[l], AD[l], asn, adn, 10);
            aggregate_out_kernel<10><<<N_NODES, 256, 0, stream>>>(
                Hb, asn, adn, rowptr, col, BI[l], (float*)d_out);
        }
        lda = 256;
    }
    (void)in_sizes; (void)n_in; (void)out_size; (void)ws_size;
}

// Round 10
// 927.639 us; speedup vs baseline: 1.3570x; 1.0061x over previous
//
#include <hip/hip_runtime.h>
#include <hip/hip_bf16.h>
#include <math.h>

#define N_NODES 50000
#define N_PAD   50048   // 391 * 128
#define N_EDGES 800000
#define HEADS 4

typedef __attribute__((ext_vector_type(8))) _Float16 half8_t;
typedef __attribute__((ext_vector_type(4))) _Float16 half4_t;
typedef __attribute__((ext_vector_type(4))) float f32x4;

// 2-way f16 split: v ~= (float)p0 + (float)p1, exact to ~2^-23 relative.
__device__ inline void split2(float v, _Float16& p0, _Float16& p1) {
    p0 = (_Float16)v;
    p1 = (_Float16)(v - (float)p0);
}

// Swizzled k-tiled plane layout (consumed by gemm via global_load_lds):
//   elem (row, k) at  (k>>5)*rows*32 + row*32 + ((((k>>3)&3) ^ (row&3))<<3) + (k&7)
// The XOR bakes the LDS bank-swizzle into global memory so the linear
// global_load_lds copy lands pre-swizzled (both-sides-or-neither rule).

// ---------------------------------------------------------------------------
// CSR construction
// ---------------------------------------------------------------------------

__global__ void init_deg_kernel(int* __restrict__ deg) {
    int i = blockIdx.x * blockDim.x + threadIdx.x;
    if (i < N_NODES) deg[i] = 1;  // self-loop
}

__global__ void hist_kernel(const int* __restrict__ dst, int* __restrict__ deg) {
    int i = blockIdx.x * blockDim.x + threadIdx.x;
    if (i < N_EDGES) atomicAdd(&deg[dst[i]], 1);
}

// Wave-coalesced two-phase scan (16 waves, contiguous chunks).
__global__ __launch_bounds__(1024) void scan_kernel(const int* __restrict__ deg,
                                                    int* __restrict__ rowptr,
                                                    int* __restrict__ cursor) {
    __shared__ int wsums[16];
    const int t = threadIdx.x;
    const int wv = t >> 6, ln = t & 63;
    const int WCHUNK = (N_NODES + 15) / 16;   // 3125
    const int base = wv * WCHUNK;
    int lim = base + WCHUNK; if (lim > N_NODES) lim = N_NODES;

    int tot = 0;
    for (int i = base + ln; i < lim; i += 64) tot += deg[i];
#pragma unroll
    for (int o = 1; o < 64; o <<= 1) tot += __shfl_xor(tot, o);
    if (ln == 0) wsums[wv] = tot;
    __syncthreads();

    int run = 0;
    for (int w = 0; w < wv; ++w) run += wsums[w];

    for (int i0 = base; i0 < lim; i0 += 64) {
        int i = i0 + ln;
        int d = (i < lim) ? deg[i] : 0;
        int sc = d;
#pragma unroll
        for (int o = 1; o < 64; o <<= 1) {
            int v = __shfl_up(sc, o);
            if (ln >= o) sc += v;
        }
        if (i < lim) {
            int val = run + sc - d;
            rowptr[i] = val;
            cursor[i] = val;
        }
        run += __shfl(sc, 63);
    }
    if (t == 1023) rowptr[N_NODES] = run;
}

__global__ void scatter_kernel(const int* __restrict__ src, const int* __restrict__ dst,
                               int* __restrict__ cursor, int* __restrict__ col) {
    int i = blockIdx.x * blockDim.x + threadIdx.x;
    if (i < N_EDGES) {
        int d = dst[i];
        int pos = atomicAdd(&cursor[d], 1);
        col[pos] = src[i];
    } else if (i < N_EDGES + N_NODES) {
        int n = i - N_EDGES;
        int pos = atomicAdd(&cursor[n], 1);
        col[pos] = n;
    }
}

// ---------------------------------------------------------------------------
// Splitters -> swizzled k-tiled planes
// ---------------------------------------------------------------------------

__global__ void x_split_kernel(const float* __restrict__ x, _Float16* __restrict__ pl,
                               size_t pstride) {
    int i = blockIdx.x * blockDim.x + threadIdx.x;
    if (i >= N_NODES * 64) return;
    int n = i >> 6, k = i & 63;
    _Float16 a, b;
    split2(x[i], a, b);
    size_t off = (size_t)(k >> 5) * ((size_t)N_PAD * 32) + (size_t)n * 32 +
                 ((((k >> 3) & 3) ^ (n & 3)) << 3) + (k & 7);
    pl[off] = a;
    pl[pstride + off] = b;
}

__global__ void w_split_kernel(const float* __restrict__ W, _Float16* __restrict__ wt,
                               int K, int NC) {
    int t = blockIdx.x * blockDim.x + threadIdx.x;  // 65536 = 256 cols x 256 k
    int c = t >> 8, k = t & 255;
    float v = (k < K && c < NC) ? W[k * NC + c] : 0.f;
    _Float16 a, b;
    split2(v, a, b);
    size_t off = (size_t)(k >> 5) * 8192 + (size_t)c * 32 +
                 ((((k >> 3) & 3) ^ (c & 3)) << 3) + (k & 7);
    wt[off] = a;
    wt[65536 + off] = b;
}

// ---------------------------------------------------------------------------
// f16x2 MFMA GEMM with global_load_lds staging (m97-style 2-barrier loop).
// Wave w stages one 8KB plane-slab: w0->A.p0, w1->A.p1, w2->B.p0, w3->B.p1.
// LDS linear [A p0|A p1|B p0|B p1], reads via the baked-in XOR swizzle.
// FUSE_ATTN=1 (layers 0-3): emit h as 2 row-major f16 planes + fused asn/adn.
// FUSE_ATTN=0 (layer 4):   write f32 C.
// 3 MFMAs per (i,j): a0b0 + a0b1 + a1b0  (a1b1 ~ 2^-22, dropped).
// ---------------------------------------------------------------------------

template <int FUSE_ATTN>
__global__ __launch_bounds__(256) void gemm_mfma_kernel(
        const _Float16* __restrict__ Apl, size_t apstride,
        const _Float16* __restrict__ Wt,   // swizzled k-tiled [2][8kt][256c][32]
        _Float16* __restrict__ hpl, size_t hstride,
        float* __restrict__ C, int K, int NC,
        const float* __restrict__ as_flat, const float* __restrict__ ad_flat,
        float* __restrict__ asn, float* __restrict__ adn) {
    __shared__ __align__(16) _Float16 lds[16384];   // 32KB

    const int tid = threadIdx.x;
    const int lane = tid & 63;
    const int wave = tid >> 6;
    const int wr = (wave >> 1) * 64;
    const int wc = (wave & 1) * 64;
    const int m0 = blockIdx.x * 128;
    const int n0 = blockIdx.y * 128;

    f32x4 acc[4][4];
#pragma unroll
    for (int i = 0; i < 4; ++i)
#pragma unroll
        for (int j = 0; j < 4; ++j) acc[i][j] = (f32x4){0.f, 0.f, 0.f, 0.f};

    // staging sources for this wave's plane-slab
    const _Float16* gptr[8];
    size_t ktstep;
    {
        const _Float16* sbase;
        int rowbase;
        if (wave < 2) {
            sbase = Apl + (size_t)wave * apstride;
            rowbase = m0;
            ktstep = (size_t)N_PAD * 32;
        } else {
            sbase = Wt + (size_t)(wave - 2) * 65536;
            rowbase = n0;
            ktstep = 8192;
        }
#pragma unroll
        for (int it = 0; it < 8; ++it) {
            int idx = it * 64 + lane;
            gptr[it] = sbase + (size_t)(rowbase + (idx >> 2)) * 32 + (idx & 3) * 8;
        }
    }
    char* ldsw = (char*)lds + wave * 8192;

    const int cswz = ((lane >> 4) ^ (lane & 3)) << 3;   // elems
    const _Float16* Ab = lds;            // 2 x [128][32]
    const _Float16* Bb = lds + 8192;

    const int KT = K >> 5;
    for (int kt = 0; kt < KT; ++kt) {
        if (kt) __syncthreads();       // all waves done reading prev tile
#pragma unroll
        for (int it = 0; it < 8; ++it) {
            __builtin_amdgcn_global_load_lds(
                (const __attribute__((address_space(1))) void*)(gptr[it] + kt * ktstep),
                (__attribute__((address_space(3))) void*)(ldsw + it * 1024),
                16, 0, 0);
        }
        __syncthreads();               // compiler drains vmcnt(0) before barrier

        half8_t bf[2][4];
#pragma unroll
        for (int p = 0; p < 2; ++p)
#pragma unroll
            for (int j = 0; j < 4; ++j) {
                int r = wc + j * 16 + (lane & 15);
                bf[p][j] = *(const half8_t*)(Bb + p * 4096 + r * 32 + cswz);
            }
#pragma unroll
        for (int i = 0; i < 4; ++i) {
            int r = wr + i * 16 + (lane & 15);
            half8_t af0 = *(const half8_t*)(Ab + r * 32 + cswz);
            half8_t af1 = *(const half8_t*)(Ab + 4096 + r * 32 + cswz);
#pragma unroll
            for (int j = 0; j < 4; ++j) {
                f32x4 c = acc[i][j];
                c = __builtin_amdgcn_mfma_f32_16x16x32_f16(af0, bf[1][j], c, 0, 0, 0);
                c = __builtin_amdgcn_mfma_f32_16x16x32_f16(af1, bf[0][j], c, 0, 0, 0);
                c = __builtin_amdgcn_mfma_f32_16x16x32_f16(af0, bf[0][j], c, 0, 0, 0);
                acc[i][j] = c;
            }
        }
    }

    // epilogue: C/D mapping col = lane&15, row = (lane>>4)*4 + reg
    const int rbase = m0 + wr + (lane >> 4) * 4;
    const int cbase = n0 + wc + (lane & 15);

    if (FUSE_ATTN) {
        // h -> 2 row-major f16 planes (NC == 256)
#pragma unroll
        for (int i = 0; i < 4; ++i)
#pragma unroll
            for (int j = 0; j < 4; ++j) {
                int gcol = cbase + j * 16;
#pragma unroll
                for (int r4 = 0; r4 < 4; ++r4) {
                    int grow = rbase + i * 16 + r4;
                    if (grow < N_NODES) {
                        _Float16 a, b;
                        split2(acc[i][j][r4], a, b);
                        size_t off = (size_t)grow * 256 + gcol;
                        hpl[off] = a;
                        hpl[hstride + off] = b;
                    }
                }
            }
        // fused asn/adn: this wave's 64 cols == head (n0+wc)>>6 (CH=64)
        const int hd_out = (n0 + wc) >> 6;
        float as_v[4], ad_v[4];
#pragma unroll
        for (int j = 0; j < 4; ++j) {
            int gc = cbase + j * 16;
            as_v[j] = as_flat[gc];
            ad_v[j] = ad_flat[gc];
        }
#pragma unroll
        for (int i = 0; i < 4; ++i)
#pragma unroll
            for (int r4 = 0; r4 < 4; ++r4) {
                float ps = 0.f, pd = 0.f;
#pragma unroll
                for (int j = 0; j < 4; ++j) {
                    float v = acc[i][j][r4];
                    ps += v * as_v[j];
                    pd += v * ad_v[j];
                }
#pragma unroll
                for (int o = 1; o < 16; o <<= 1) {
                    ps += __shfl_xor(ps, o);
                    pd += __shfl_xor(pd, o);
                }
                if ((lane & 15) == 0) {
                    int grow = rbase + i * 16 + r4;
                    if (grow < N_NODES) {
                        asn[grow * 4 + hd_out] = ps;
                        adn[grow * 4 + hd_out] = pd;
                    }
                }
            }
    } else {
#pragma unroll
        for (int i = 0; i < 4; ++i)
#pragma unroll
            for (int j = 0; j < 4; ++j) {
                int gcol = cbase + j * 16;
                if (gcol >= NC) continue;
#pragma unroll
                for (int r4 = 0; r4 < 4; ++r4) {
                    int grow = rbase + i * 16 + r4;
                    if (grow < N_NODES) C[(size_t)grow * NC + gcol] = acc[i][j][r4];
                }
            }
    }
}

// ---------------------------------------------------------------------------
// Standalone attention coefficients (layer 4 only, CH=10)
// ---------------------------------------------------------------------------

__global__ void attn_coef_kernel(const float* __restrict__ h,
                                 const float* __restrict__ a_s,
                                 const float* __restrict__ a_d,
                                 float* __restrict__ asn, float* __restrict__ adn,
                                 int CH) {
    int t = blockIdx.x * blockDim.x + threadIdx.x;
    if (t >= N_NODES * HEADS) return;
    int n = t >> 2;
    int hd = t & 3;
    const float* hp = h + (size_t)n * HEADS * CH + hd * CH;
    const float* sp = a_s + hd * CH;
    const float* dp = a_d + hd * CH;
    float s1 = 0.f, s2 = 0.f;
    for (int c = 0; c < CH; c += 2) {
        float2 hv = *reinterpret_cast<const float2*>(&hp[c]);
        float2 av = *reinterpret_cast<const float2*>(&sp[c]);
        float2 dv = *reinterpret_cast<const float2*>(&dp[c]);
        s1 += hv.x * av.x + hv.y * av.y;
        s2 += hv.x * dv.x + hv.y * dv.y;
    }
    asn[t] = s1;
    adn[t] = s2;
}

// ---------------------------------------------------------------------------
// One-wave-per-node aggregation (CH=64 layers): whole 256-col row per wave,
// coalesced reads from 2 row-major f16 planes; per-head softmax in 16-lane
// groups. Emits the next GEMM's A in swizzled k-tiled layout.
// ---------------------------------------------------------------------------

__global__ __launch_bounds__(256) void aggregate64_kernel(
        const _Float16* __restrict__ hpl, size_t hstride,
        const float* __restrict__ asn, const float* __restrict__ adn,
        const int* __restrict__ rowptr, const int* __restrict__ col,
        const float* __restrict__ bias,
        _Float16* __restrict__ pl, size_t pstride) {
    const int n = (blockIdx.x << 2) + (threadIdx.x >> 6);
    const int lane = threadIdx.x & 63;
    const int hd = lane >> 4;
    const int e16 = lane & 15;
    const int pbase = lane & 48;

    const int start = rowptr[n];
    const int end = rowptr[n + 1];
    const float adv = adn[(n << 2) | hd];

    float m = -INFINITY, s = 0.f;
    float a0 = 0.f, a1 = 0.f, a2 = 0.f, a3 = 0.f;

    for (int e0 = start; e0 < end; e0 += 16) {
        int e = e0 + e16;
        int srcl = n;
        float ev = -INFINITY;
        if (e < end) {
            srcl = col[e];
            float t = asn[(srcl << 2) | hd] + adv;
            ev = (t > 0.f) ? t : 0.2f * t;   // leaky_relu(0.2)
        }
        float bm = ev;
#pragma unroll
        for (int o = 1; o < 16; o <<= 1) bm = fmaxf(bm, __shfl_xor(bm, o));
        float mn = fmaxf(m, bm);
        float scale = __expf(m - mn);
        float p = __expf(ev - mn);
        float ps = p;
#pragma unroll
        for (int o = 1; o < 16; o <<= 1) ps += __shfl_xor(ps, o);
        s = s * scale + ps;
        a0 *= scale; a1 *= scale; a2 *= scale; a3 *= scale;
        m = mn;

        int cnt = end - e0; if (cnt > 16) cnt = 16;
        int cnt4 = (cnt + 3) & ~3;
        for (int j0 = 0; j0 < cnt4; j0 += 4) {
            int sj[4]; float pj[4];
#pragma unroll
            for (int j = 0; j < 4; ++j) {
                sj[j] = __shfl(srcl, j0 + j);
                pj[j] = __shfl(p, pbase + j0 + j);
            }
            half4_t h0[4], h1[4];
#pragma unroll
            for (int j = 0; j < 4; ++j) {
                const _Float16* hp = hpl + (size_t)sj[j] * 256 + (lane << 2);
                h0[j] = *(const half4_t*)hp;
                h1[j] = *(const half4_t*)(hp + hstride);
            }
#pragma unroll
            for (int j = 0; j < 4; ++j) {
                a0 += pj[j] * ((float)h0[j][0] + (float)h1[j][0]);
                a1 += pj[j] * ((float)h0[j][1] + (float)h1[j][1]);
                a2 += pj[j] * ((float)h0[j][2] + (float)h1[j][2]);
                a3 += pj[j] * ((float)h0[j][3] + (float)h1[j][3]);
            }
        }
    }

    float sd = s + 1e-16f;
    const float* bp = bias + (lane << 2);
    float v0 = fmaxf(a0 / sd + bp[0], 0.f);
    float v1 = fmaxf(a1 / sd + bp[1], 0.f);
    float v2 = fmaxf(a2 / sd + bp[2], 0.f);
    float v3 = fmaxf(a3 / sd + bp[3], 0.f);

    _Float16 s0a, s0b, s1a, s1b, s2a, s2b, s3a, s3b;
    split2(v0, s0a, s0b);
    split2(v1, s1a, s1b);
    split2(v2, s2a, s2b);
    split2(v3, s3a, s3b);
    half4_t o0, o1;
    o0[0] = s0a; o0[1] = s1a; o0[2] = s2a; o0[3] = s3a;
    o1[0] = s0b; o1[1] = s1b; o1[2] = s2b; o1[3] = s3b;

    // swizzled k-tiled emit: k = lane*4..+3
    const int kt = lane >> 3;
    const int cp = ((lane >> 1) & 3) ^ (n & 3);
    const int inner = (lane & 1) << 2;
    size_t off = (size_t)kt * ((size_t)N_PAD * 32) + (size_t)n * 32 + (cp << 3) + inner;
    *(half4_t*)(pl + off) = o0;
    *(half4_t*)(pl + pstride + off) = o1;
}

// ---------------------------------------------------------------------------
// Layer-4 aggregation (CH=10), f32 h, writes d_out.
// ---------------------------------------------------------------------------

template <int CH>
__global__ __launch_bounds__(256) void aggregate_out_kernel(
        const float* __restrict__ h, const float* __restrict__ asn,
        const float* __restrict__ adn, const int* __restrict__ rowptr,
        const int* __restrict__ col, const float* __restrict__ bias,
        float* __restrict__ out) {
    constexpr int HC = HEADS * CH;
    __shared__ float2 pair_lds[HEADS][32];

    const int n = blockIdx.x;
    const int hd = threadIdx.x >> 6;
    const int lane = threadIdx.x & 63;
    const int el = lane & 31;
    const int hdoff = hd * CH + lane;

    const int start = rowptr[n];
    const int end = rowptr[n + 1];
    const float adv = adn[(n << 2) | hd];

    float m = -INFINITY, s = 0.f;
    float accv[4] = {0.f, 0.f, 0.f, 0.f};

    for (int e0 = start; e0 < end; e0 += 32) {
        int e = e0 + el;
        bool valid = (lane < 32) && (e < end);
        int srcl = n;
        float ev = -INFINITY;
        if (valid) {
            srcl = col[e];
            float t = asn[(srcl << 2) | hd] + adv;
            ev = (t > 0.f) ? t : 0.2f * t;
        }
        float bm = ev;
#pragma unroll
        for (int o = 1; o < 64; o <<= 1) bm = fmaxf(bm, __shfl_xor(bm, o));
        float mn = fmaxf(m, bm);
        float scale = __expf(m - mn);
        float p = __expf(ev - mn);
        float ps = p;
#pragma unroll
        for (int o = 1; o < 64; o <<= 1) ps += __shfl_xor(ps, o);
        s = s * scale + ps;
#pragma unroll
        for (int c = 0; c < 4; ++c) accv[c] *= scale;
        m = mn;

        if (lane < 32) pair_lds[hd][lane] = make_float2(__int_as_float(srcl), p);

        int cnt = end - e0; if (cnt > 32) cnt = 32;
        int cnt8 = (cnt + 7) & ~7;
        for (int i0 = 0; i0 < cnt8; i0 += 8) {
            int sv[8]; float pv[8];
#pragma unroll
            for (int j = 0; j < 8; ++j) {
                float2 pr = pair_lds[hd][i0 + j];
                sv[j] = __float_as_int(pr.x);
                pv[j] = pr.y;
            }
            float hv[8];
#pragma unroll
            for (int j = 0; j < 8; ++j)
                hv[j] = (lane < CH) ? h[(size_t)sv[j] * HC + hdoff] : 0.f;
#pragma unroll
            for (int j = 0; j < 8; ++j) accv[j & 3] += pv[j] * hv[j];
        }
    }

    if (lane < CH) {
        float acc = (accv[0] + accv[1]) + (accv[2] + accv[3]);
        float v = acc / (s + 1e-16f) + bias[hd * CH + lane];
        out[n * HC + hd * CH + lane] = fmaxf(v, 0.f);
    }
}

// ---------------------------------------------------------------------------

extern "C" void kernel_launch(void* const* d_in, const int* in_sizes, int n_in,
                              void* d_out, int out_size, void* d_ws, size_t ws_size,
                              hipStream_t stream) {
    const float* x_in = (const float*)d_in[0];
    const int* ei = (const int*)d_in[1];
    const int* src = ei;
    const int* dst = ei + N_EDGES;

    const float *W[5], *AS[5], *AD[5], *BI[5];
    for (int l = 0; l < 5; ++l) {
        W[l]  = (const float*)d_in[2 + l * 4 + 0];
        AS[l] = (const float*)d_in[2 + l * 4 + 1];
        AD[l] = (const float*)d_in[2 + l * 4 + 2];
        BI[l] = (const float*)d_in[2 + l * 4 + 3];
    }

    // workspace carve-up
    const size_t PSTRIDE = (size_t)N_PAD * 256;           // elements per plane
    _Float16* planes = (_Float16*)d_ws;                   // GEMM A planes (2, swizzled k-tiled)
    _Float16* hpl = planes + 2 * PSTRIDE;                 // h planes (2, row-major)
    float* Hb   = (float*)(hpl + 2 * PSTRIDE);            // N x 40 f32 (layer 4)
    float* asn  = Hb + (size_t)N_NODES * 40;
    float* adn  = asn + (size_t)N_NODES * HEADS;
    int* rowptr = (int*)(adn + (size_t)N_NODES * HEADS);  // N+1
    int* cursor = rowptr + (N_NODES + 1);
    int* col    = cursor + N_NODES;                       // E + N
    _Float16* wt = (_Float16*)(((uintptr_t)(col + N_EDGES + N_NODES) + 15) & ~(uintptr_t)15);

    // --- CSR build ---
    init_deg_kernel<<<(N_NODES + 255) / 256, 256, 0, stream>>>(cursor);
    hist_kernel<<<(N_EDGES + 255) / 256, 256, 0, stream>>>(dst, cursor);
    scan_kernel<<<1, 1024, 0, stream>>>(cursor, rowptr, cursor);
    scatter_kernel<<<(N_EDGES + N_NODES + 255) / 256, 256, 0, stream>>>(src, dst, cursor, col);

    // --- weight & input splits (swizzled k-tiled) ---
    for (int l = 0; l < 5; ++l) {
        int Kl = (l == 0) ? 64 : 256;
        int NCl = (l == 4) ? 40 : 256;
        w_split_kernel<<<256, 256, 0, stream>>>(W[l], wt + (size_t)l * 2 * 65536, Kl, NCl);
    }
    x_split_kernel<<<(N_NODES * 64 + 255) / 256, 256, 0, stream>>>(x_in, planes, PSTRIDE);

    // --- 5 GAT layers ---
    for (int l = 0; l < 5; ++l) {
        const int K = (l == 0) ? 64 : 256;
        const int NC = (l == 4) ? 40 : 256;
        dim3 ggrid(N_PAD / 128, (NC + 127) / 128);
        const _Float16* wl = wt + (size_t)l * 2 * 65536;
        if (l < 4) {
            gemm_mfma_kernel<1><<<ggrid, 256, 0, stream>>>(
                planes, PSTRIDE, wl, hpl, PSTRIDE, nullptr, K, NC,
                AS[l], AD[l], asn, adn);
            aggregate64_kernel<<<N_NODES / 4, 256, 0, stream>>>(
                hpl, PSTRIDE, asn, adn, rowptr, col, BI[l], planes, PSTRIDE);
        } else {
            gemm_mfma_kernel<0><<<ggrid, 256, 0, stream>>>(
                planes, PSTRIDE, wl, nullptr, 0, Hb, K, NC,
                AS[l], AD[l], asn, adn);
            attn_coef_kernel<<<(N_NODES * HEADS + 255) / 256, 256, 0, stream>>>(
                Hb, AS[l], AD[l], asn, adn, 10);
            aggregate_out_kernel<10><<<N_NODES, 256, 0, stream>>>(
                Hb, asn, adn, rowptr, col, BI[l], (float*)d_out);
        }
    }
    (void)in_sizes; (void)n_in; (void)out_size; (void)ws_size;
}

// Round 11
// 913.866 us; speedup vs baseline: 1.3775x; 1.0151x over previous
//
#include <hip/hip_runtime.h>
#include <hip/hip_bf16.h>
#include <math.h>

#define N_NODES 50000
#define N_PAD   50048   // 391 * 128
#define N_EDGES 800000
#define HEADS 4

typedef __attribute__((ext_vector_type(8))) _Float16 half8_t;
typedef __attribute__((ext_vector_type(4))) _Float16 half4_t;
typedef __attribute__((ext_vector_type(4))) float f32x4;

// 2-way f16 split: v ~= (float)p0 + (float)p1, exact to ~2^-23 relative.
__device__ inline void split2(float v, _Float16& p0, _Float16& p1) {
    p0 = (_Float16)v;
    p1 = (_Float16)(v - (float)p0);
}

// Swizzled k-tiled plane layout (consumed by gemm via global_load_lds):
//   elem (row, k) at  (k>>5)*rows*32 + row*32 + ((((k>>3)&3) ^ (row&3))<<3) + (k&7)
// The XOR bakes the LDS bank-swizzle into global memory so the linear
// global_load_lds copy lands pre-swizzled (both-sides-or-neither rule).

// ---------------------------------------------------------------------------
// CSR construction
// ---------------------------------------------------------------------------

__global__ void init_deg_kernel(int* __restrict__ deg) {
    int i = blockIdx.x * blockDim.x + threadIdx.x;
    if (i < N_NODES) deg[i] = 1;  // self-loop
}

__global__ void hist_kernel(const int* __restrict__ dst, int* __restrict__ deg) {
    int i = blockIdx.x * blockDim.x + threadIdx.x;
    if (i < N_EDGES) atomicAdd(&deg[dst[i]], 1);
}

// Wave-coalesced two-phase scan (16 waves, contiguous chunks).
__global__ __launch_bounds__(1024) void scan_kernel(const int* __restrict__ deg,
                                                    int* __restrict__ rowptr,
                                                    int* __restrict__ cursor) {
    __shared__ int wsums[16];
    const int t = threadIdx.x;
    const int wv = t >> 6, ln = t & 63;
    const int WCHUNK = (N_NODES + 15) / 16;   // 3125
    const int base = wv * WCHUNK;
    int lim = base + WCHUNK; if (lim > N_NODES) lim = N_NODES;

    int tot = 0;
    for (int i = base + ln; i < lim; i += 64) tot += deg[i];
#pragma unroll
    for (int o = 1; o < 64; o <<= 1) tot += __shfl_xor(tot, o);
    if (ln == 0) wsums[wv] = tot;
    __syncthreads();

    int run = 0;
    for (int w = 0; w < wv; ++w) run += wsums[w];

    for (int i0 = base; i0 < lim; i0 += 64) {
        int i = i0 + ln;
        int d = (i < lim) ? deg[i] : 0;
        int sc = d;
#pragma unroll
        for (int o = 1; o < 64; o <<= 1) {
            int v = __shfl_up(sc, o);
            if (ln >= o) sc += v;
        }
        if (i < lim) {
            int val = run + sc - d;
            rowptr[i] = val;
            cursor[i] = val;
        }
        run += __shfl(sc, 63);
    }
    if (t == 1023) rowptr[N_NODES] = run;
}

__global__ void scatter_kernel(const int* __restrict__ src, const int* __restrict__ dst,
                               int* __restrict__ cursor, int* __restrict__ col) {
    int i = blockIdx.x * blockDim.x + threadIdx.x;
    if (i < N_EDGES) {
        int d = dst[i];
        int pos = atomicAdd(&cursor[d], 1);
        col[pos] = src[i];
    } else if (i < N_EDGES + N_NODES) {
        int n = i - N_EDGES;
        int pos = atomicAdd(&cursor[n], 1);
        col[pos] = n;
    }
}

// ---------------------------------------------------------------------------
// Splitters -> swizzled k-tiled planes
// ---------------------------------------------------------------------------

__global__ void x_split_kernel(const float* __restrict__ x, _Float16* __restrict__ pl,
                               size_t pstride) {
    int i = blockIdx.x * blockDim.x + threadIdx.x;
    if (i >= N_NODES * 64) return;
    int n = i >> 6, k = i & 63;
    _Float16 a, b;
    split2(x[i], a, b);
    size_t off = (size_t)(k >> 5) * ((size_t)N_PAD * 32) + (size_t)n * 32 +
                 ((((k >> 3) & 3) ^ (n & 3)) << 3) + (k & 7);
    pl[off] = a;
    pl[pstride + off] = b;
}

__global__ void w_split_kernel(const float* __restrict__ W, _Float16* __restrict__ wt,
                               int K, int NC) {
    int t = blockIdx.x * blockDim.x + threadIdx.x;  // 65536 = 256 cols x 256 k
    int c = t >> 8, k = t & 255;
    float v = (k < K && c < NC) ? W[k * NC + c] : 0.f;
    _Float16 a, b;
    split2(v, a, b);
    size_t off = (size_t)(k >> 5) * 8192 + (size_t)c * 32 +
                 ((((k >> 3) & 3) ^ (c & 3)) << 3) + (k & 7);
    wt[off] = a;
    wt[65536 + off] = b;
}

// ---------------------------------------------------------------------------
// f16x2 MFMA GEMM, double-buffered global_load_lds staging (T3 2-phase):
// one barrier per k-tile; next-tile loads issued BEFORE compute so HBM/L2
// latency hides under the MFMA+ds_read phase.
// Wave w stages one 8KB plane-slab: w0->A.p0, w1->A.p1, w2->B.p0, w3->B.p1.
// FUSE_ATTN=1 (layers 0-3): emit h as 2 row-major f16 planes + fused asn/adn.
// FUSE_ATTN=0 (layer 4):   write f32 C.
// 3 MFMAs per (i,j): a0b0 + a0b1 + a1b0  (a1b1 ~ 2^-22, dropped).
// ---------------------------------------------------------------------------

template <int FUSE_ATTN>
__global__ __launch_bounds__(256) void gemm_mfma_kernel(
        const _Float16* __restrict__ Apl, size_t apstride,
        const _Float16* __restrict__ Wt,   // swizzled k-tiled [2][8kt][256c][32]
        _Float16* __restrict__ hpl, size_t hstride,
        float* __restrict__ C, int K, int NC,
        const float* __restrict__ as_flat, const float* __restrict__ ad_flat,
        float* __restrict__ asn, float* __restrict__ adn) {
    __shared__ __align__(16) _Float16 lds[2][16384];   // 2 x 32KB

    const int tid = threadIdx.x;
    const int lane = tid & 63;
    const int wave = tid >> 6;
    const int wr = (wave >> 1) * 64;
    const int wc = (wave & 1) * 64;
    const int m0 = blockIdx.x * 128;
    const int n0 = blockIdx.y * 128;

    f32x4 acc[4][4];
#pragma unroll
    for (int i = 0; i < 4; ++i)
#pragma unroll
        for (int j = 0; j < 4; ++j) acc[i][j] = (f32x4){0.f, 0.f, 0.f, 0.f};

    // staging sources for this wave's plane-slab
    const _Float16* gptr[8];
    size_t ktstep;
    {
        const _Float16* sbase;
        int rowbase;
        if (wave < 2) {
            sbase = Apl + (size_t)wave * apstride;
            rowbase = m0;
            ktstep = (size_t)N_PAD * 32;
        } else {
            sbase = Wt + (size_t)(wave - 2) * 65536;
            rowbase = n0;
            ktstep = 8192;
        }
#pragma unroll
        for (int it = 0; it < 8; ++it) {
            int idx = it * 64 + lane;
            gptr[it] = sbase + (size_t)(rowbase + (idx >> 2)) * 32 + (idx & 3) * 8;
        }
    }

    const int cswz = ((lane >> 4) ^ (lane & 3)) << 3;   // elems
    const int KT = K >> 5;

    // prologue: stage tile 0 into buf 0
#pragma unroll
    for (int it = 0; it < 8; ++it) {
        __builtin_amdgcn_global_load_lds(
            (const __attribute__((address_space(1))) void*)gptr[it],
            (__attribute__((address_space(3))) void*)((char*)&lds[0][0] + wave * 8192 + it * 1024),
            16, 0, 0);
    }

    for (int kt = 0; kt < KT; ++kt) {
        __syncthreads();   // drains my in-flight loads (buf[kt&1] ready) and
                           // guarantees all waves done reading buf[(kt+1)&1]

        // issue next-tile loads BEFORE compute: latency hides under MFMA phase
        if (kt + 1 < KT) {
            char* dstw = (char*)&lds[(kt + 1) & 1][0] + wave * 8192;
#pragma unroll
            for (int it = 0; it < 8; ++it) {
                __builtin_amdgcn_global_load_lds(
                    (const __attribute__((address_space(1))) void*)(gptr[it] + (size_t)(kt + 1) * ktstep),
                    (__attribute__((address_space(3))) void*)(dstw + it * 1024),
                    16, 0, 0);
            }
        }

        const _Float16* Ab = &lds[kt & 1][0];
        const _Float16* Bb = Ab + 8192;

        half8_t bf[2][4];
#pragma unroll
        for (int p = 0; p < 2; ++p)
#pragma unroll
            for (int j = 0; j < 4; ++j) {
                int r = wc + j * 16 + (lane & 15);
                bf[p][j] = *(const half8_t*)(Bb + p * 4096 + r * 32 + cswz);
            }
#pragma unroll
        for (int i = 0; i < 4; ++i) {
            int r = wr + i * 16 + (lane & 15);
            half8_t af0 = *(const half8_t*)(Ab + r * 32 + cswz);
            half8_t af1 = *(const half8_t*)(Ab + 4096 + r * 32 + cswz);
#pragma unroll
            for (int j = 0; j < 4; ++j) {
                f32x4 c = acc[i][j];
                c = __builtin_amdgcn_mfma_f32_16x16x32_f16(af0, bf[1][j], c, 0, 0, 0);
                c = __builtin_amdgcn_mfma_f32_16x16x32_f16(af1, bf[0][j], c, 0, 0, 0);
                c = __builtin_amdgcn_mfma_f32_16x16x32_f16(af0, bf[0][j], c, 0, 0, 0);
                acc[i][j] = c;
            }
        }
    }

    // epilogue: C/D mapping col = lane&15, row = (lane>>4)*4 + reg
    const int rbase = m0 + wr + (lane >> 4) * 4;
    const int cbase = n0 + wc + (lane & 15);

    if (FUSE_ATTN) {
        // h -> 2 row-major f16 planes (NC == 256)
#pragma unroll
        for (int i = 0; i < 4; ++i)
#pragma unroll
            for (int j = 0; j < 4; ++j) {
                int gcol = cbase + j * 16;
#pragma unroll
                for (int r4 = 0; r4 < 4; ++r4) {
                    int grow = rbase + i * 16 + r4;
                    if (grow < N_NODES) {
                        _Float16 a, b;
                        split2(acc[i][j][r4], a, b);
                        size_t off = (size_t)grow * 256 + gcol;
                        hpl[off] = a;
                        hpl[hstride + off] = b;
                    }
                }
            }
        // fused asn/adn: this wave's 64 cols == head (n0+wc)>>6 (CH=64)
        const int hd_out = (n0 + wc) >> 6;
        float as_v[4], ad_v[4];
#pragma unroll
        for (int j = 0; j < 4; ++j) {
            int gc = cbase + j * 16;
            as_v[j] = as_flat[gc];
            ad_v[j] = ad_flat[gc];
        }
#pragma unroll
        for (int i = 0; i < 4; ++i)
#pragma unroll
            for (int r4 = 0; r4 < 4; ++r4) {
                float ps = 0.f, pd = 0.f;
#pragma unroll
                for (int j = 0; j < 4; ++j) {
                    float v = acc[i][j][r4];
                    ps += v * as_v[j];
                    pd += v * ad_v[j];
                }
#pragma unroll
                for (int o = 1; o < 16; o <<= 1) {
                    ps += __shfl_xor(ps, o);
                    pd += __shfl_xor(pd, o);
                }
                if ((lane & 15) == 0) {
                    int grow = rbase + i * 16 + r4;
                    if (grow < N_NODES) {
                        asn[grow * 4 + hd_out] = ps;
                        adn[grow * 4 + hd_out] = pd;
                    }
                }
            }
    } else {
#pragma unroll
        for (int i = 0; i < 4; ++i)
#pragma unroll
            for (int j = 0; j < 4; ++j) {
                int gcol = cbase + j * 16;
                if (gcol >= NC) continue;
#pragma unroll
                for (int r4 = 0; r4 < 4; ++r4) {
                    int grow = rbase + i * 16 + r4;
                    if (grow < N_NODES) C[(size_t)grow * NC + gcol] = acc[i][j][r4];
                }
            }
    }
}

// ---------------------------------------------------------------------------
// Standalone attention coefficients (layer 4 only, CH=10)
// ---------------------------------------------------------------------------

__global__ void attn_coef_kernel(const float* __restrict__ h,
                                 const float* __restrict__ a_s,
                                 const float* __restrict__ a_d,
                                 float* __restrict__ asn, float* __restrict__ adn,
                                 int CH) {
    int t = blockIdx.x * blockDim.x + threadIdx.x;
    if (t >= N_NODES * HEADS) return;
    int n = t >> 2;
    int hd = t & 3;
    const float* hp = h + (size_t)n * HEADS * CH + hd * CH;
    const float* sp = a_s + hd * CH;
    const float* dp = a_d + hd * CH;
    float s1 = 0.f, s2 = 0.f;
    for (int c = 0; c < CH; c += 2) {
        float2 hv = *reinterpret_cast<const float2*>(&hp[c]);
        float2 av = *reinterpret_cast<const float2*>(&sp[c]);
        float2 dv = *reinterpret_cast<const float2*>(&dp[c]);
        s1 += hv.x * av.x + hv.y * av.y;
        s2 += hv.x * dv.x + hv.y * dv.y;
    }
    asn[t] = s1;
    adn[t] = s2;
}

// ---------------------------------------------------------------------------
// One-wave-per-node aggregation (CH=64 layers): whole 256-col row per wave,
// coalesced reads from 2 row-major f16 planes; per-head softmax in 16-lane
// groups. Emits the next GEMM's A in swizzled k-tiled layout.
// ---------------------------------------------------------------------------

__global__ __launch_bounds__(256) void aggregate64_kernel(
        const _Float16* __restrict__ hpl, size_t hstride,
        const float* __restrict__ asn, const float* __restrict__ adn,
        const int* __restrict__ rowptr, const int* __restrict__ col,
        const float* __restrict__ bias,
        _Float16* __restrict__ pl, size_t pstride) {
    const int n = (blockIdx.x << 2) + (threadIdx.x >> 6);
    const int lane = threadIdx.x & 63;
    const int hd = lane >> 4;
    const int e16 = lane & 15;
    const int pbase = lane & 48;

    const int start = rowptr[n];
    const int end = rowptr[n + 1];
    const float adv = adn[(n << 2) | hd];

    float m = -INFINITY, s = 0.f;
    float a0 = 0.f, a1 = 0.f, a2 = 0.f, a3 = 0.f;

    for (int e0 = start; e0 < end; e0 += 16) {
        int e = e0 + e16;
        int srcl = n;
        float ev = -INFINITY;
        if (e < end) {
            srcl = col[e];
            float t = asn[(srcl << 2) | hd] + adv;
            ev = (t > 0.f) ? t : 0.2f * t;   // leaky_relu(0.2)
        }
        float bm = ev;
#pragma unroll
        for (int o = 1; o < 16; o <<= 1) bm = fmaxf(bm, __shfl_xor(bm, o));
        float mn = fmaxf(m, bm);
        float scale = __expf(m - mn);
        float p = __expf(ev - mn);
        float ps = p;
#pragma unroll
        for (int o = 1; o < 16; o <<= 1) ps += __shfl_xor(ps, o);
        s = s * scale + ps;
        a0 *= scale; a1 *= scale; a2 *= scale; a3 *= scale;
        m = mn;

        int cnt = end - e0; if (cnt > 16) cnt = 16;
        int cnt4 = (cnt + 3) & ~3;
        for (int j0 = 0; j0 < cnt4; j0 += 4) {
            int sj[4]; float pj[4];
#pragma unroll
            for (int j = 0; j < 4; ++j) {
                sj[j] = __shfl(srcl, j0 + j);
                pj[j] = __shfl(p, pbase + j0 + j);
            }
            half4_t h0[4], h1[4];
#pragma unroll
            for (int j = 0; j < 4; ++j) {
                const _Float16* hp = hpl + (size_t)sj[j] * 256 + (lane << 2);
                h0[j] = *(const half4_t*)hp;
                h1[j] = *(const half4_t*)(hp + hstride);
            }
#pragma unroll
            for (int j = 0; j < 4; ++j) {
                a0 += pj[j] * ((float)h0[j][0] + (float)h1[j][0]);
                a1 += pj[j] * ((float)h0[j][1] + (float)h1[j][1]);
                a2 += pj[j] * ((float)h0[j][2] + (float)h1[j][2]);
                a3 += pj[j] * ((float)h0[j][3] + (float)h1[j][3]);
            }
        }
    }

    float sd = s + 1e-16f;
    const float* bp = bias + (lane << 2);
    float v0 = fmaxf(a0 / sd + bp[0], 0.f);
    float v1 = fmaxf(a1 / sd + bp[1], 0.f);
    float v2 = fmaxf(a2 / sd + bp[2], 0.f);
    float v3 = fmaxf(a3 / sd + bp[3], 0.f);

    _Float16 s0a, s0b, s1a, s1b, s2a, s2b, s3a, s3b;
    split2(v0, s0a, s0b);
    split2(v1, s1a, s1b);
    split2(v2, s2a, s2b);
    split2(v3, s3a, s3b);
    half4_t o0, o1;
    o0[0] = s0a; o0[1] = s1a; o0[2] = s2a; o0[3] = s3a;
    o1[0] = s0b; o1[1] = s1b; o1[2] = s2b; o1[3] = s3b;

    // swizzled k-tiled emit: k = lane*4..+3
    const int kt = lane >> 3;
    const int cp = ((lane >> 1) & 3) ^ (n & 3);
    const int inner = (lane & 1) << 2;
    size_t off = (size_t)kt * ((size_t)N_PAD * 32) + (size_t)n * 32 + (cp << 3) + inner;
    *(half4_t*)(pl + off) = o0;
    *(half4_t*)(pl + pstride + off) = o1;
}

// ---------------------------------------------------------------------------
// Layer-4 aggregation (CH=10), f32 h, writes d_out.
// ---------------------------------------------------------------------------

template <int CH>
__global__ __launch_bounds__(256) void aggregate_out_kernel(
        const float* __restrict__ h, const float* __restrict__ asn,
        const float* __restrict__ adn, const int* __restrict__ rowptr,
        const int* __restrict__ col, const float* __restrict__ bias,
        float* __restrict__ out) {
    constexpr int HC = HEADS * CH;
    __shared__ float2 pair_lds[HEADS][32];

    const int n = blockIdx.x;
    const int hd = threadIdx.x >> 6;
    const int lane = threadIdx.x & 63;
    const int el = lane & 31;
    const int hdoff = hd * CH + lane;

    const int start = rowptr[n];
    const int end = rowptr[n + 1];
    const float adv = adn[(n << 2) | hd];

    float m = -INFINITY, s = 0.f;
    float accv[4] = {0.f, 0.f, 0.f, 0.f};

    for (int e0 = start; e0 < end; e0 += 32) {
        int e = e0 + el;
        bool valid = (lane < 32) && (e < end);
        int srcl = n;
        float ev = -INFINITY;
        if (valid) {
            srcl = col[e];
            float t = asn[(srcl << 2) | hd] + adv;
            ev = (t > 0.f) ? t : 0.2f * t;
        }
        float bm = ev;
#pragma unroll
        for (int o = 1; o < 64; o <<= 1) bm = fmaxf(bm, __shfl_xor(bm, o));
        float mn = fmaxf(m, bm);
        float scale = __expf(m - mn);
        float p = __expf(ev - mn);
        float ps = p;
#pragma unroll
        for (int o = 1; o < 64; o <<= 1) ps += __shfl_xor(ps, o);
        s = s * scale + ps;
#pragma unroll
        for (int c = 0; c < 4; ++c) accv[c] *= scale;
        m = mn;

        if (lane < 32) pair_lds[hd][lane] = make_float2(__int_as_float(srcl), p);

        int cnt = end - e0; if (cnt > 32) cnt = 32;
        int cnt8 = (cnt + 7) & ~7;
        for (int i0 = 0; i0 < cnt8; i0 += 8) {
            int sv[8]; float pv[8];
#pragma unroll
            for (int j = 0; j < 8; ++j) {
                float2 pr = pair_lds[hd][i0 + j];
                sv[j] = __float_as_int(pr.x);
                pv[j] = pr.y;
            }
            float hv[8];
#pragma unroll
            for (int j = 0; j < 8; ++j)
                hv[j] = (lane < CH) ? h[(size_t)sv[j] * HC + hdoff] : 0.f;
#pragma unroll
            for (int j = 0; j < 8; ++j) accv[j & 3] += pv[j] * hv[j];
        }
    }

    if (lane < CH) {
        float acc = (accv[0] + accv[1]) + (accv[2] + accv[3]);
        float v = acc / (s + 1e-16f) + bias[hd * CH + lane];
        out[n * HC + hd * CH + lane] = fmaxf(v, 0.f);
    }
}

// ---------------------------------------------------------------------------

extern "C" void kernel_launch(void* const* d_in, const int* in_sizes, int n_in,
                              void* d_out, int out_size, void* d_ws, size_t ws_size,
                              hipStream_t stream) {
    const float* x_in = (const float*)d_in[0];
    const int* ei = (const int*)d_in[1];
    const int* src = ei;
    const int* dst = ei + N_EDGES;

    const float *W[5], *AS[5], *AD[5], *BI[5];
    for (int l = 0; l < 5; ++l) {
        W[l]  = (const float*)d_in[2 + l * 4 + 0];
        AS[l] = (const float*)d_in[2 + l * 4 + 1];
        AD[l] = (const float*)d_in[2 + l * 4 + 2];
        BI[l] = (const float*)d_in[2 + l * 4 + 3];
    }

    // workspace carve-up
    const size_t PSTRIDE = (size_t)N_PAD * 256;           // elements per plane
    _Float16* planes = (_Float16*)d_ws;                   // GEMM A planes (2, swizzled k-tiled)
    _Float16* hpl = planes + 2 * PSTRIDE;                 // h planes (2, row-major)
    float* Hb   = (float*)(hpl + 2 * PSTRIDE);            // N x 40 f32 (layer 4)
    float* asn  = Hb + (size_t)N_NODES * 40;
    float* adn  = asn + (size_t)N_NODES * HEADS;
    int* rowptr = (int*)(adn + (size_t)N_NODES * HEADS);  // N+1
    int* cursor = rowptr + (N_NODES + 1);
    int* col    = cursor + N_NODES;                       // E + N
    _Float16* wt = (_Float16*)(((uintptr_t)(col + N_EDGES + N_NODES) + 15) & ~(uintptr_t)15);

    // --- CSR build ---
    init_deg_kernel<<<(N_NODES + 255) / 256, 256, 0, stream>>>(cursor);
    hist_kernel<<<(N_EDGES + 255) / 256, 256, 0, stream>>>(dst, cursor);
    scan_kernel<<<1, 1024, 0, stream>>>(cursor, rowptr, cursor);
    scatter_kernel<<<(N_EDGES + N_NODES + 255) / 256, 256, 0, stream>>>(src, dst, cursor, col);

    // --- weight & input splits (swizzled k-tiled) ---
    for (int l = 0; l < 5; ++l) {
        int Kl = (l == 0) ? 64 : 256;
        int NCl = (l == 4) ? 40 : 256;
        w_split_kernel<<<256, 256, 0, stream>>>(W[l], wt + (size_t)l * 2 * 65536, Kl, NCl);
    }
    x_split_kernel<<<(N_NODES * 64 + 255) / 256, 256, 0, stream>>>(x_in, planes, PSTRIDE);

    // --- 5 GAT layers ---
    for (int l = 0; l < 5; ++l) {
        const int K = (l == 0) ? 64 : 256;
        const int NC = (l == 4) ? 40 : 256;
        dim3 ggrid(N_PAD / 128, (NC + 127) / 128);
        const _Float16* wl = wt + (size_t)l * 2 * 65536;
        if (l < 4) {
            gemm_mfma_kernel<1><<<ggrid, 256, 0, stream>>>(
                planes, PSTRIDE, wl, hpl, PSTRIDE, nullptr, K, NC,
                AS[l], AD[l], asn, adn);
            aggregate64_kernel<<<N_NODES / 4, 256, 0, stream>>>(
                hpl, PSTRIDE, asn, adn, rowptr, col, BI[l], planes, PSTRIDE);
        } else {
            gemm_mfma_kernel<0><<<ggrid, 256, 0, stream>>>(
                planes, PSTRIDE, wl, nullptr, 0, Hb, K, NC,
                AS[l], AD[l], asn, adn);
            attn_coef_kernel<<<(N_NODES * HEADS + 255) / 256, 256, 0, stream>>>(
                Hb, AS[l], AD[l], asn, adn, 10);
            aggregate_out_kernel<10><<<N_NODES, 256, 0, stream>>>(
                Hb, asn, adn, rowptr, col, BI[l], (float*)d_out);
        }
    }
    (void)in_sizes; (void)n_in; (void)out_size; (void)ws_size;
}

// Round 13
// 842.621 us; speedup vs baseline: 1.4939x; 1.0846x over previous
//
#include <hip/hip_runtime.h>
#include <hip/hip_bf16.h>
#include <math.h>

#define N_NODES 50000
#define N_PAD   50048   // 391 * 128
#define N_EDGES 800000
#define HEADS 4

typedef __attribute__((ext_vector_type(8))) _Float16 half8_t;
typedef __attribute__((ext_vector_type(4))) _Float16 half4_t;
typedef __attribute__((ext_vector_type(4))) float f32x4;

// 2-way f16 split: v ~= (float)p0 + (float)p1, exact to ~2^-23 relative.
__device__ inline void split2(float v, _Float16& p0, _Float16& p1) {
    p0 = (_Float16)v;
    p1 = (_Float16)(v - (float)p0);
}

// Swizzled k-tiled plane layout (A and W planes, staged via global_load_lds):
//   elem (row, k) at  (k>>5)*rows*32 + row*32 + ((((k>>3)&3) ^ (row&3))<<3) + (k&7)

// ---------------------------------------------------------------------------
// CSR construction
// ---------------------------------------------------------------------------

__global__ void init_deg_kernel(int* __restrict__ deg) {
    int i = blockIdx.x * blockDim.x + threadIdx.x;
    if (i < N_NODES) deg[i] = 1;  // self-loop
}

__global__ void hist_kernel(const int* __restrict__ dst, int* __restrict__ deg) {
    int i = blockIdx.x * blockDim.x + threadIdx.x;
    if (i < N_EDGES) atomicAdd(&deg[dst[i]], 1);
}

// Wave-coalesced two-phase scan (16 waves, contiguous chunks).
__global__ __launch_bounds__(1024) void scan_kernel(const int* __restrict__ deg,
                                                    int* __restrict__ rowptr,
                                                    int* __restrict__ cursor) {
    __shared__ int wsums[16];
    const int t = threadIdx.x;
    const int wv = t >> 6, ln = t & 63;
    const int WCHUNK = (N_NODES + 15) / 16;   // 3125
    const int base = wv * WCHUNK;
    int lim = base + WCHUNK; if (lim > N_NODES) lim = N_NODES;

    int tot = 0;
    for (int i = base + ln; i < lim; i += 64) tot += deg[i];
#pragma unroll
    for (int o = 1; o < 64; o <<= 1) tot += __shfl_xor(tot, o);
    if (ln == 0) wsums[wv] = tot;
    __syncthreads();

    int run = 0;
    for (int w = 0; w < wv; ++w) run += wsums[w];

    for (int i0 = base; i0 < lim; i0 += 64) {
        int i = i0 + ln;
        int d = (i < lim) ? deg[i] : 0;
        int sc = d;
#pragma unroll
        for (int o = 1; o < 64; o <<= 1) {
            int v = __shfl_up(sc, o);
            if (ln >= o) sc += v;
        }
        if (i < lim) {
            int val = run + sc - d;
            rowptr[i] = val;
            cursor[i] = val;
        }
        run += __shfl(sc, 63);
    }
    if (t == 1023) rowptr[N_NODES] = run;
}

__global__ void scatter_kernel(const int* __restrict__ src, const int* __restrict__ dst,
                               int* __restrict__ cursor, int* __restrict__ col) {
    int i = blockIdx.x * blockDim.x + threadIdx.x;
    if (i < N_EDGES) {
        int d = dst[i];
        int pos = atomicAdd(&cursor[d], 1);
        col[pos] = src[i];
    } else if (i < N_EDGES + N_NODES) {
        int n = i - N_EDGES;
        int pos = atomicAdd(&cursor[n], 1);
        col[pos] = n;
    }
}

// ---------------------------------------------------------------------------
// Splitters -> swizzled k-tiled planes
// ---------------------------------------------------------------------------

__global__ void x_split_kernel(const float* __restrict__ x, _Float16* __restrict__ pl,
                               size_t pstride) {
    int i = blockIdx.x * blockDim.x + threadIdx.x;
    if (i >= N_NODES * 64) return;
    int n = i >> 6, k = i & 63;
    _Float16 a, b;
    split2(x[i], a, b);
    size_t off = (size_t)(k >> 5) * ((size_t)N_PAD * 32) + (size_t)n * 32 +
                 ((((k >> 3) & 3) ^ (n & 3)) << 3) + (k & 7);
    pl[off] = a;
    pl[pstride + off] = b;
}

__global__ void w_split_kernel(const float* __restrict__ W, _Float16* __restrict__ wt,
                               int K, int NC) {
    int t = blockIdx.x * blockDim.x + threadIdx.x;  // 65536 = 256 cols x 256 k
    int c = t >> 8, k = t & 255;
    float v = (k < K && c < NC) ? W[k * NC + c] : 0.f;
    _Float16 a, b;
    split2(v, a, b);
    size_t off = (size_t)(k >> 5) * 8192 + (size_t)c * 32 +
                 ((((k >> 3) & 3) ^ (c & 3)) << 3) + (k & 7);
    wt[off] = a;
    wt[65536 + off] = b;
}

// ---------------------------------------------------------------------------
// f16x2 MFMA GEMM, double-buffered global_load_lds staging (round-11 proven
// structure): wave w stages one 8KB plane-slab (w0->A.p0, w1->A.p1,
// w2->B.p0, w3->B.p1); one barrier per k-tile, next-tile loads issued
// before compute.
// FUSE_ATTN=1 (layers 0-3): C = f32 h [N][256] + fused asn/adn epilogue.
// FUSE_ATTN=0 (layer 4):   C = f32 [N][NC] guarded.
// 3 MFMAs per (i,j): a0b0 + a0b1 + a1b0  (a1b1 ~ 2^-22, dropped).
// ---------------------------------------------------------------------------

template <int FUSE_ATTN>
__global__ __launch_bounds__(256) void gemm_mfma_kernel(
        const _Float16* __restrict__ Apl, size_t apstride,
        const _Float16* __restrict__ Wt,   // swizzled k-tiled [2][kt][256][32]
        float* __restrict__ C, int K, int NC,
        const float* __restrict__ as_flat, const float* __restrict__ ad_flat,
        float* __restrict__ asn, float* __restrict__ adn) {
    __shared__ __align__(16) _Float16 lds[2][16384];   // 2 x 32KB

    const int tid = threadIdx.x;
    const int lane = tid & 63;
    const int wave = tid >> 6;
    const int wr = (wave >> 1) * 64;
    const int wc = (wave & 1) * 64;
    const int m0 = blockIdx.x * 128;
    const int n0 = blockIdx.y * 128;

    f32x4 acc[4][4];
#pragma unroll
    for (int i = 0; i < 4; ++i)
#pragma unroll
        for (int j = 0; j < 4; ++j) acc[i][j] = (f32x4){0.f, 0.f, 0.f, 0.f};

    // staging sources for this wave's plane-slab
    const _Float16* gptr[8];
    size_t ktstep;
    {
        const _Float16* sbase;
        int rowbase;
        if (wave < 2) {
            sbase = Apl + (size_t)wave * apstride;
            rowbase = m0;
            ktstep = (size_t)N_PAD * 32;
        } else {
            sbase = Wt + (size_t)(wave - 2) * 65536;
            rowbase = n0;
            ktstep = 8192;
        }
#pragma unroll
        for (int it = 0; it < 8; ++it) {
            int idx = it * 64 + lane;
            gptr[it] = sbase + (size_t)(rowbase + (idx >> 2)) * 32 + (idx & 3) * 8;
        }
    }

    const int cswz = ((lane >> 4) ^ (lane & 3)) << 3;   // elems
    const int KT = K >> 5;

    // prologue: stage tile 0 into buf 0
#pragma unroll
    for (int it = 0; it < 8; ++it) {
        __builtin_amdgcn_global_load_lds(
            (const __attribute__((address_space(1))) void*)gptr[it],
            (__attribute__((address_space(3))) void*)((char*)&lds[0][0] + wave * 8192 + it * 1024),
            16, 0, 0);
    }

    for (int kt = 0; kt < KT; ++kt) {
        __syncthreads();   // drains my in-flight loads (buf[kt&1] ready) and
                           // guarantees all waves done reading buf[(kt+1)&1]

        if (kt + 1 < KT) {
            char* dstw = (char*)&lds[(kt + 1) & 1][0] + wave * 8192;
#pragma unroll
            for (int it = 0; it < 8; ++it) {
                __builtin_amdgcn_global_load_lds(
                    (const __attribute__((address_space(1))) void*)(gptr[it] + (size_t)(kt + 1) * ktstep),
                    (__attribute__((address_space(3))) void*)(dstw + it * 1024),
                    16, 0, 0);
            }
        }

        const _Float16* Ab = &lds[kt & 1][0];
        const _Float16* Bb = Ab + 8192;

        half8_t bf[2][4];
#pragma unroll
        for (int p = 0; p < 2; ++p)
#pragma unroll
            for (int j = 0; j < 4; ++j) {
                int r = wc + j * 16 + (lane & 15);
                bf[p][j] = *(const half8_t*)(Bb + p * 4096 + r * 32 + cswz);
            }
#pragma unroll
        for (int i = 0; i < 4; ++i) {
            int r = wr + i * 16 + (lane & 15);
            half8_t af0 = *(const half8_t*)(Ab + r * 32 + cswz);
            half8_t af1 = *(const half8_t*)(Ab + 4096 + r * 32 + cswz);
#pragma unroll
            for (int j = 0; j < 4; ++j) {
                f32x4 c = acc[i][j];
                c = __builtin_amdgcn_mfma_f32_16x16x32_f16(af0, bf[1][j], c, 0, 0, 0);
                c = __builtin_amdgcn_mfma_f32_16x16x32_f16(af1, bf[0][j], c, 0, 0, 0);
                c = __builtin_amdgcn_mfma_f32_16x16x32_f16(af0, bf[0][j], c, 0, 0, 0);
                acc[i][j] = c;
            }
        }
    }

    // epilogue: C/D mapping col = lane&15, row = (lane>>4)*4 + reg
    const int rbase = m0 + wr + (lane >> 4) * 4;
    const int cbase = n0 + wc + (lane & 15);

    if (FUSE_ATTN) {
        // h -> f32 [N][256]
#pragma unroll
        for (int i = 0; i < 4; ++i)
#pragma unroll
            for (int j = 0; j < 4; ++j) {
                int gcol = cbase + j * 16;
#pragma unroll
                for (int r4 = 0; r4 < 4; ++r4) {
                    int grow = rbase + i * 16 + r4;
                    if (grow < N_NODES) C[(size_t)grow * 256 + gcol] = acc[i][j][r4];
                }
            }
        // fused asn/adn: this wave's 64 cols == head (n0+wc)>>6 (CH=64)
        const int hd_out = (n0 + wc) >> 6;
        float as_v[4], ad_v[4];
#pragma unroll
        for (int j = 0; j < 4; ++j) {
            int gc = cbase + j * 16;
            as_v[j] = as_flat[gc];
            ad_v[j] = ad_flat[gc];
        }
#pragma unroll
        for (int i = 0; i < 4; ++i)
#pragma unroll
            for (int r4 = 0; r4 < 4; ++r4) {
                float ps = 0.f, pd = 0.f;
#pragma unroll
                for (int j = 0; j < 4; ++j) {
                    float v = acc[i][j][r4];
                    ps += v * as_v[j];
                    pd += v * ad_v[j];
                }
#pragma unroll
                for (int o = 1; o < 16; o <<= 1) {
                    ps += __shfl_xor(ps, o);
                    pd += __shfl_xor(pd, o);
                }
                if ((lane & 15) == 0) {
                    int grow = rbase + i * 16 + r4;
                    if (grow < N_NODES) {
                        asn[grow * 4 + hd_out] = ps;
                        adn[grow * 4 + hd_out] = pd;
                    }
                }
            }
    } else {
#pragma unroll
        for (int i = 0; i < 4; ++i)
#pragma unroll
            for (int j = 0; j < 4; ++j) {
                int gcol = cbase + j * 16;
                if (gcol >= NC) continue;
#pragma unroll
                for (int r4 = 0; r4 < 4; ++r4) {
                    int grow = rbase + i * 16 + r4;
                    if (grow < N_NODES) C[(size_t)grow * NC + gcol] = acc[i][j][r4];
                }
            }
    }
}

// ---------------------------------------------------------------------------
// Standalone attention coefficients (layer 4 only, CH=10)
// ---------------------------------------------------------------------------

__global__ void attn_coef_kernel(const float* __restrict__ h,
                                 const float* __restrict__ a_s,
                                 const float* __restrict__ a_d,
                                 float* __restrict__ asn, float* __restrict__ adn,
                                 int CH) {
    int t = blockIdx.x * blockDim.x + threadIdx.x;
    if (t >= N_NODES * HEADS) return;
    int n = t >> 2;
    int hd = t & 3;
    const float* hp = h + (size_t)n * HEADS * CH + hd * CH;
    const float* sp = a_s + hd * CH;
    const float* dp = a_d + hd * CH;
    float s1 = 0.f, s2 = 0.f;
    for (int c = 0; c < CH; c += 2) {
        float2 hv = *reinterpret_cast<const float2*>(&hp[c]);
        float2 av = *reinterpret_cast<const float2*>(&sp[c]);
        float2 dv = *reinterpret_cast<const float2*>(&dp[c]);
        s1 += hv.x * av.x + hv.y * av.y;
        s2 += hv.x * dv.x + hv.y * dv.y;
    }
    asn[t] = s1;
    adn[t] = s2;
}

// ---------------------------------------------------------------------------
// One-wave-per-node aggregation (CH=64 layers): lane = 4-channel block of the
// 256-col row; one float4 per lane per edge (1KB coalesced wave-read, f32 h).
// Per-head softmax in 16-lane groups; p/src broadcast via shfl.
// Emits the next GEMM's A in swizzled k-tiled f16x2 layout.
// ---------------------------------------------------------------------------

__global__ __launch_bounds__(256) void aggregate64_kernel(
        const float* __restrict__ h,   // [N][256] f32
        const float* __restrict__ asn, const float* __restrict__ adn,
        const int* __restrict__ rowptr, const int* __restrict__ col,
        const float* __restrict__ bias,
        _Float16* __restrict__ pl, size_t pstride) {
    const int n = (blockIdx.x << 2) + (threadIdx.x >> 6);
    const int lane = threadIdx.x & 63;
    const int hd = lane >> 4;
    const int e16 = lane & 15;
    const int pbase = lane & 48;

    const int start = rowptr[n];
    const int end = rowptr[n + 1];
    const float adv = adn[(n << 2) | hd];

    float m = -INFINITY, s = 0.f;
    float a0 = 0.f, a1 = 0.f, a2 = 0.f, a3 = 0.f;

    for (int e0 = start; e0 < end; e0 += 16) {
        int e = e0 + e16;
        int srcl = n;
        float ev = -INFINITY;
        if (e < end) {
            srcl = col[e];
            float t = asn[(srcl << 2) | hd] + adv;
            ev = (t > 0.f) ? t : 0.2f * t;   // leaky_relu(0.2)
        }
        float bm = ev;
#pragma unroll
        for (int o = 1; o < 16; o <<= 1) bm = fmaxf(bm, __shfl_xor(bm, o));
        float mn = fmaxf(m, bm);
        float scale = __expf(m - mn);
        float p = __expf(ev - mn);
        float ps = p;
#pragma unroll
        for (int o = 1; o < 16; o <<= 1) ps += __shfl_xor(ps, o);
        s = s * scale + ps;
        a0 *= scale; a1 *= scale; a2 *= scale; a3 *= scale;
        m = mn;

        int cnt = end - e0; if (cnt > 16) cnt = 16;
        int cnt4 = (cnt + 3) & ~3;
        for (int j0 = 0; j0 < cnt4; j0 += 4) {
            int sj[4]; float pj[4];
#pragma unroll
            for (int j = 0; j < 4; ++j) {
                sj[j] = __shfl(srcl, j0 + j);
                pj[j] = __shfl(p, pbase + j0 + j);
            }
            float4 hv[4];
#pragma unroll
            for (int j = 0; j < 4; ++j)
                hv[j] = *reinterpret_cast<const float4*>(h + (size_t)sj[j] * 256 + (lane << 2));
#pragma unroll
            for (int j = 0; j < 4; ++j) {
                a0 += pj[j] * hv[j].x;
                a1 += pj[j] * hv[j].y;
                a2 += pj[j] * hv[j].z;
                a3 += pj[j] * hv[j].w;
            }
        }
    }

    float sd = s + 1e-16f;
    const float* bp = bias + (lane << 2);
    float v0 = fmaxf(a0 / sd + bp[0], 0.f);
    float v1 = fmaxf(a1 / sd + bp[1], 0.f);
    float v2 = fmaxf(a2 / sd + bp[2], 0.f);
    float v3 = fmaxf(a3 / sd + bp[3], 0.f);

    _Float16 s0a, s0b, s1a, s1b, s2a, s2b, s3a, s3b;
    split2(v0, s0a, s0b);
    split2(v1, s1a, s1b);
    split2(v2, s2a, s2b);
    split2(v3, s3a, s3b);
    half4_t o0, o1;
    o0[0] = s0a; o0[1] = s1a; o0[2] = s2a; o0[3] = s3a;
    o1[0] = s0b; o1[1] = s1b; o1[2] = s2b; o1[3] = s3b;

    // swizzled k-tiled emit: k = lane*4..+3
    const int kt = lane >> 3;
    const int cp = ((lane >> 1) & 3) ^ (n & 3);
    const int inner = (lane & 1) << 2;
    size_t off = (size_t)kt * ((size_t)N_PAD * 32) + (size_t)n * 32 + (cp << 3) + inner;
    *(half4_t*)(pl + off) = o0;
    *(half4_t*)(pl + pstride + off) = o1;
}

// ---------------------------------------------------------------------------
// Layer-4 aggregation (CH=10): one wave per node. Lanes 0..39 gather the
// whole 160B h-row per edge; softmax per head in 16-lane groups; p routed
// to channel lanes via shfl. Writes d_out.
// ---------------------------------------------------------------------------

__global__ __launch_bounds__(256) void aggregate_out10_kernel(
        const float* __restrict__ h,   // [N][40] f32
        const float* __restrict__ asn, const float* __restrict__ adn,
        const int* __restrict__ rowptr, const int* __restrict__ col,
        const float* __restrict__ bias, float* __restrict__ out) {
    const int n = (blockIdx.x << 2) + (threadIdx.x >> 6);
    const int lane = threadIdx.x & 63;
    const int hd16 = lane >> 4;          // softmax-role head
    const int e16 = lane & 15;
    const bool cvalid = lane < 40;
    const int hc = ((cvalid ? lane : 0) * 205) >> 11;   // lane/10: channel head

    const int start = rowptr[n];
    const int end = rowptr[n + 1];
    const float adv = adn[(n << 2) | hd16];

    float m = -INFINITY, s = 0.f, a0 = 0.f, a1 = 0.f;

    for (int e0 = start; e0 < end; e0 += 16) {
        int e = e0 + e16;
        int srcl = n;
        float ev = -INFINITY;
        if (e < end) {
            srcl = col[e];
            float t = asn[(srcl << 2) | hd16] + adv;
            ev = (t > 0.f) ? t : 0.2f * t;
        }
        float bm = ev;
#pragma unroll
        for (int o = 1; o < 16; o <<= 1) bm = fmaxf(bm, __shfl_xor(bm, o));
        float mn = fmaxf(m, bm);
        float scale = __expf(m - mn);
        float p = __expf(ev - mn);
        float ps = p;
#pragma unroll
        for (int o = 1; o < 16; o <<= 1) ps += __shfl_xor(ps, o);
        s = s * scale + ps;
        m = mn;

        float sc_c = __shfl(scale, hc * 16);   // my channel-head's scale
        a0 *= sc_c;
        a1 *= sc_c;

        int cnt = end - e0; if (cnt > 16) cnt = 16;
        int cnt4 = (cnt + 3) & ~3;
        for (int j0 = 0; j0 < cnt4; j0 += 4) {
            int sj[4]; float pj[4];
#pragma unroll
            for (int j = 0; j < 4; ++j) {
                sj[j] = __shfl(srcl, j0 + j);
                pj[j] = __shfl(p, hc * 16 + j0 + j);
            }
            float hv[4];
#pragma unroll
            for (int j = 0; j < 4; ++j)
                hv[j] = cvalid ? h[(size_t)sj[j] * 40 + lane] : 0.f;
            a0 += pj[0] * hv[0];
            a1 += pj[1] * hv[1];
            a0 += pj[2] * hv[2];
            a1 += pj[3] * hv[3];
        }
    }

    float sd = __shfl(s, hc * 16) + 1e-16f;
    if (cvalid) {
        float v = (a0 + a1) / sd + bias[lane];
        out[(size_t)n * 40 + lane] = fmaxf(v, 0.f);
    }
}

// ---------------------------------------------------------------------------

extern "C" void kernel_launch(void* const* d_in, const int* in_sizes, int n_in,
                              void* d_out, int out_size, void* d_ws, size_t ws_size,
                              hipStream_t stream) {
    const float* x_in = (const float*)d_in[0];
    const int* ei = (const int*)d_in[1];
    const int* src = ei;
    const int* dst = ei + N_EDGES;

    const float *W[5], *AS[5], *AD[5], *BI[5];
    for (int l = 0; l < 5; ++l) {
        W[l]  = (const float*)d_in[2 + l * 4 + 0];
        AS[l] = (const float*)d_in[2 + l * 4 + 1];
        AD[l] = (const float*)d_in[2 + l * 4 + 2];
        BI[l] = (const float*)d_in[2 + l * 4 + 3];
    }

    // workspace carve-up
    const size_t PSTRIDE = (size_t)N_PAD * 256;           // elements per plane
    _Float16* planes = (_Float16*)d_ws;                   // GEMM A planes (2, swizzled k-tiled)
    float* hbuf = (float*)(planes + 2 * PSTRIDE);         // h f32 [N][256] (layer4: [N][40])
    float* asn  = hbuf + (size_t)N_NODES * 256;
    float* adn  = asn + (size_t)N_NODES * HEADS;
    int* rowptr = (int*)(adn + (size_t)N_NODES * HEADS);  // N+1
    int* cursor = rowptr + (N_NODES + 1);
    int* col    = cursor + N_NODES;                       // E + N
    _Float16* wt = (_Float16*)(((uintptr_t)(col + N_EDGES + N_NODES) + 15) & ~(uintptr_t)15);

    // --- CSR build ---
    init_deg_kernel<<<(N_NODES + 255) / 256, 256, 0, stream>>>(cursor);
    hist_kernel<<<(N_EDGES + 255) / 256, 256, 0, stream>>>(dst, cursor);
    scan_kernel<<<1, 1024, 0, stream>>>(cursor, rowptr, cursor);
    scatter_kernel<<<(N_EDGES + N_NODES + 255) / 256, 256, 0, stream>>>(src, dst, cursor, col);

    // --- weight & input splits (swizzled k-tiled) ---
    for (int l = 0; l < 5; ++l) {
        int Kl = (l == 0) ? 64 : 256;
        int NCl = (l == 4) ? 40 : 256;
        w_split_kernel<<<256, 256, 0, stream>>>(W[l], wt + (size_t)l * 131072, Kl, NCl);
    }
    x_split_kernel<<<(N_NODES * 64 + 255) / 256, 256, 0, stream>>>(x_in, planes, PSTRIDE);

    // --- 5 GAT layers ---
    for (int l = 0; l < 5; ++l) {
        const int K = (l == 0) ? 64 : 256;
        const int NC = (l == 4) ? 40 : 256;
        dim3 ggrid(N_PAD / 128, (NC + 127) / 128);
        const _Float16* wl = wt + (size_t)l * 131072;
        if (l < 4) {
            gemm_mfma_kernel<1><<<ggrid, 256, 0, stream>>>(
                planes, PSTRIDE, wl, hbuf, K, NC, AS[l], AD[l], asn, adn);
            aggregate64_kernel<<<N_NODES / 4, 256, 0, stream>>>(
                hbuf, asn, adn, rowptr, col, BI[l], planes, PSTRIDE);
        } else {
            gemm_mfma_kernel<0><<<ggrid, 256, 0, stream>>>(
                planes, PSTRIDE, wl, hbuf, K, NC, AS[l], AD[l], asn, adn);
            attn_coef_kernel<<<(N_NODES * HEADS + 255) / 256, 256, 0, stream>>>(
                hbuf, AS[l], AD[l], asn, adn, 10);
            aggregate_out10_kernel<<<N_NODES / 4, 256, 0, stream>>>(
                hbuf, asn, adn, rowptr, col, BI[l], (float*)d_out);
        }
    }
    (void)in_sizes; (void)n_in; (void)out_size; (void)ws_size;
}